// Round 5
// baseline (454.358 us; speedup 1.0000x reference)
//
#include <hip/hip_runtime.h>
#include <hip/hip_bf16.h>

#define B_   64
#define N_   512
#define T_   8
#define DIN_ 2
#define H_   256
#define L_   3
#define E_   8192
#define M_   128
#define P2_  24   // P*2
#define EPS_ 1e-5f

#define TILE 64
#define KC   16
#define WTPAD 136

typedef __attribute__((ext_vector_type(8))) short short8;
typedef __attribute__((ext_vector_type(4))) float floatx4;

__device__ __forceinline__ unsigned short f2bf(float f) {
    union { float f; unsigned u; } v; v.f = f;
    unsigned r = v.u + 0x7FFF + ((v.u >> 16) & 1);
    return (unsigned short)(r >> 16);
}
__device__ __forceinline__ float bf2f(unsigned short h) {
    union { unsigned u; float f; } v; v.u = (unsigned)h << 16; return v.f;
}

// ---- encoder: hT[b,c,n] fp32 + actT[b,c,n] split bf16 (mean_t relu) ------
__global__ __launch_bounds__(512) void encoder2_kernel(
    const float* __restrict__ obs, const float* __restrict__ Wenc,
    const float* __restrict__ benc, float* __restrict__ hT,
    unsigned short* __restrict__ actT, long actLo)
{
    int b = blockIdx.x, h0 = blockIdx.y * 64;
    __shared__ float o[8224];  // swizzled obs[b]: idx = n*16 + (n>>6)*4 + k
    const float4* src = (const float4*)(obs + (long)b * N_ * 16);
    int tid = threadIdx.x;
    for (int i = tid; i < 2048; i += 512) {
        int n = i >> 2, k = (i & 3) << 2;
        *(float4*)&o[n * 16 + ((n >> 6) << 2) + k] = src[i];
    }
    __syncthreads();
    int c  = h0 + (tid >> 3);
    int n0 = (tid & 7) * 64;
    int swz = (n0 >> 6) << 2;
    float w0 = Wenc[c], w1 = Wenc[H_ + c], bb = benc[c];
    long rowbase = ((long)b * H_ + c) * N_;
#pragma unroll 4
    for (int j = 0; j < 64; ++j) {
        int n = n0 + j;
        const float* op = &o[n * 16 + swz];
        float acc = 0.f;
#pragma unroll
        for (int t = 0; t < T_; ++t) {
            float v = op[2 * t] * w0 + op[2 * t + 1] * w1 + bb;
            acc += fmaxf(v, 0.f);
        }
        acc *= 0.125f;
        long idx = rowbase + n;
        hT[idx] = acc;
        unsigned short hv = f2bf(acc);
        actT[idx] = hv;
        actT[actLo + idx] = f2bf(acc - bf2f(hv));
    }
}

// -------------------- densify incidence via LDS counts --------------------
__global__ __launch_bounds__(256) void build_kernel(const int* __restrict__ idx,
    unsigned short* __restrict__ Hmat, unsigned short* __restrict__ HmatT,
    float* __restrict__ DinvN, float* __restrict__ degM)
{
    int b = blockIdx.x;
    int chunk = blockIdx.y;
    int c0 = chunk * 64;
    __shared__ unsigned int cnt[64 * 129];
    for (int i = threadIdx.x; i < 64 * 129; i += 256) cnt[i] = 0;
    __syncthreads();
    const int* nodes = idx + (long)b * 2 * E_;
    const int* edges = nodes + E_;
    for (int e = threadIdx.x; e < E_; e += 256) {
        int n = nodes[e];
        if ((n >> 6) == chunk) {
            int m = edges[e];
            atomicAdd(&cnt[(n & 63) * 129 + m], 1u);
        }
    }
    __syncthreads();
    for (int i = threadIdx.x; i < 64 * 128; i += 256) {
        int r = i >> 7, m = i & 127;
        Hmat[((long)(b * N_ + c0 + r)) * M_ + m] = f2bf((float)cnt[r * 129 + m]);
    }
    for (int i = threadIdx.x; i < 64 * 128; i += 256) {
        int m = i >> 6, r = i & 63;
        HmatT[((long)(b * M_ + m)) * N_ + c0 + r] = f2bf((float)cnt[r * 129 + m]);
    }
    if (threadIdx.x < 64) {
        int r = threadIdx.x;
        unsigned s = 0;
#pragma unroll 8
        for (int m = 0; m < 128; ++m) s += cnt[r * 129 + m];
        DinvN[b * N_ + c0 + r] = 1.0f / fmaxf((float)s, 1.0f);
    } else if (threadIdx.x < 192) {
        int m = threadIdx.x - 64;
        unsigned s = 0;
#pragma unroll 8
        for (int r = 0; r < 64; ++r) s += cnt[r * 129 + m];
        atomicAdd(&degM[b * M_ + m], (float)s);
    }
}

__global__ void inv_kernel(float* deg, int n) {
    int i = blockIdx.x * blockDim.x + threadIdx.x;
    if (i < n) deg[i] = 1.0f / fmaxf(deg[i], 1.0f);
}

// ---------- fp32 [R,C] -> SPLIT bf16 [C,R] batched transpose (thetas) -----
__global__ __launch_bounds__(256) void transpose_f32_bf16split(
    const float* __restrict__ in, long inStride,
    unsigned short* __restrict__ outT, long outStride, long loOff, int R, int C)
{
    int b = blockIdx.z;
    int r0 = blockIdx.y * 64, c0 = blockIdx.x * 64;
    __shared__ float tile[64][65];
    const float* ib = in + (long)b * inStride;
    unsigned short* ob = outT + (long)b * outStride;
    int x = threadIdx.x & 63;
    int y0 = threadIdx.x >> 6;
#pragma unroll
    for (int i = 0; i < 16; ++i) {
        int y = y0 * 16 + i;
        tile[y][x] = ib[(long)(r0 + y) * C + c0 + x];
    }
    __syncthreads();
#pragma unroll
    for (int i = 0; i < 16; ++i) {
        int y = y0 * 16 + i;
        float v = tile[x][y];
        unsigned short hv = f2bf(v);
        long idx = (long)(c0 + y) * R + r0 + x;
        ob[idx] = hv;
        ob[loOff + idx] = f2bf(v - bf2f(hv));
    }
}

// ======== fused layer: Z=Binv(H^T X) ; W=Theta^T Z^T ; hc^T=Dinv(W Hm^T)+b ;
//          BN over n ; ReLU ; write split actOut.  1 block = (batch, 64 h-rows)
__global__ __launch_bounds__(512, 2) void layer_kernel(
    const unsigned short* __restrict__ HmatT,   // [B][128][512]
    const unsigned short* __restrict__ Hmat,    // [B][512][128]
    const unsigned short* __restrict__ actIn, long actLo,
    const unsigned short* __restrict__ thT, long thLo,  // pre-offset to layer
    const float* __restrict__ BinvM, const float* __restrict__ DinvN,
    const float* __restrict__ convb, const float* __restrict__ gamma,
    const float* __restrict__ beta,
    unsigned short* __restrict__ actOut)
{
    __shared__ __align__(16) char lds[51200];
    // stage1 staging (union region A)
    unsigned short* As1  = (unsigned short*)lds;            // [128][40]
    unsigned short* Bs1h = As1 + 128 * 40;                  // [256][40]
    unsigned short* Bs1l = Bs1h + 256 * 40;                 // [256][40]
    // stage2 (overlaps region A)
    unsigned short* Zch  = (unsigned short*)lds;            // [128][40]
    unsigned short* Zcl  = Zch + 128 * 40;
    unsigned short* As2h = Zcl + 128 * 40;                  // [64][40]
    unsigned short* As2l = As2h + 64 * 40;
    // stage3 (overlaps region A)
    unsigned short* Wh   = (unsigned short*)lds;            // [64][136]
    unsigned short* Wl   = Wh + 64 * WTPAD;
    float* rsum = (float*)(lds + 64 * WTPAD * 2 * 2);       // [64][8]
    float* rsq  = rsum + 512;
    float2* prm = (float2*)(rsq + 512);                     // [64]

    int b = blockIdx.y, h0 = blockIdx.x * 64;
    int tid = threadIdx.x, wave = tid >> 6, lane = tid & 63;
    int lr = lane & 15, lq = lane >> 4;

    const unsigned short* HT  = HmatT + (long)b * M_ * N_;
    const unsigned short* Hm  = Hmat + (long)b * N_ * M_;
    const unsigned short* aIn = actIn + (long)b * H_ * N_;

    // ---------------- stage 1: Z[m][h'] = Binv[m] * sum_n HT[m][n]*act[h'][n]
    int wm1 = (wave >> 2) * 64;      // {0,64}
    int wn1 = (wave & 3) * 64;       // {0,64,128,192}
    floatx4 acc1[4][4] = {};
    for (int k0 = 0; k0 < N_; k0 += 32) {
        __syncthreads();
        {
            int r = tid >> 2, ck = (tid & 3) << 3;
            *(uint4*)&As1[r * 40 + ck] = *(const uint4*)&HT[(long)r * N_ + k0 + ck];
        }
#pragma unroll
        for (int i = tid; i < 1024; i += 512) {
            int r = i >> 2, ck = (i & 3) << 3;
            *(uint4*)&Bs1h[r * 40 + ck] = *(const uint4*)&aIn[(long)r * N_ + k0 + ck];
            *(uint4*)&Bs1l[r * 40 + ck] = *(const uint4*)&aIn[actLo + (long)r * N_ + k0 + ck];
        }
        __syncthreads();
        short8 af[4], bh[4], bl[4];
#pragma unroll
        for (int mt = 0; mt < 4; ++mt)
            af[mt] = *(const short8*)&As1[(wm1 + mt * 16 + lr) * 40 + lq * 8];
#pragma unroll
        for (int nt = 0; nt < 4; ++nt) {
            bh[nt] = *(const short8*)&Bs1h[(wn1 + nt * 16 + lr) * 40 + lq * 8];
            bl[nt] = *(const short8*)&Bs1l[(wn1 + nt * 16 + lr) * 40 + lq * 8];
        }
#pragma unroll
        for (int mt = 0; mt < 4; ++mt)
#pragma unroll
            for (int nt = 0; nt < 4; ++nt) {
                acc1[mt][nt] = __builtin_amdgcn_mfma_f32_16x16x32_bf16(
                    af[mt], bh[nt], acc1[mt][nt], 0, 0, 0);
                acc1[mt][nt] = __builtin_amdgcn_mfma_f32_16x16x32_bf16(
                    af[mt], bl[nt], acc1[mt][nt], 0, 0, 0);
            }
    }
    float rsB[4][4];
#pragma unroll
    for (int mt = 0; mt < 4; ++mt)
#pragma unroll
        for (int r4 = 0; r4 < 4; ++r4)
            rsB[mt][r4] = BinvM[b * M_ + wm1 + mt * 16 + lq * 4 + r4];

    // ---------------- stage 2: W[h][m] = sum_h' thT[h][h'] * Z[m][h']
    int wm2 = (wave >> 2) * 32, wn2 = (wave & 3) * 32;
    floatx4 acc2[2][2] = {};
    for (int k0 = 0; k0 < H_; k0 += 32) {
        __syncthreads();
        // 2 waves stream their acc1 slice (cols k0..k0+32) into Zch/Zcl
        if ((wave & 3) == (k0 >> 6)) {
            int nt0 = (k0 >> 4) & 2;
#pragma unroll
            for (int ntl = 0; ntl < 4; ++ntl) {
                if ((ntl & 2) == nt0) {
                    int kk = ((ntl & 1) << 4) + lr;
#pragma unroll
                    for (int mtl = 0; mtl < 4; ++mtl)
#pragma unroll
                        for (int r4 = 0; r4 < 4; ++r4) {
                            int m = wm1 + mtl * 16 + lq * 4 + r4;
                            float v = acc1[mtl][ntl][r4] * rsB[mtl][r4];
                            unsigned short hv = f2bf(v);
                            Zch[m * 40 + kk] = hv;
                            Zcl[m * 40 + kk] = f2bf(v - bf2f(hv));
                        }
                }
            }
        }
        {
            int i = tid & 255, pl = tid >> 8;
            int r = i >> 2, ck = (i & 3) << 3;
            const unsigned short* src = thT + (pl ? thLo : 0) + (long)(h0 + r) * H_ + k0 + ck;
            *(uint4*)((pl ? As2l : As2h) + r * 40 + ck) = *(const uint4*)src;
        }
        __syncthreads();
        short8 ah[2], al[2], zb[2], zl[2];
#pragma unroll
        for (int mt = 0; mt < 2; ++mt) {
            ah[mt] = *(const short8*)&As2h[(wm2 + mt * 16 + lr) * 40 + lq * 8];
            al[mt] = *(const short8*)&As2l[(wm2 + mt * 16 + lr) * 40 + lq * 8];
        }
#pragma unroll
        for (int nt = 0; nt < 2; ++nt) {
            zb[nt] = *(const short8*)&Zch[(wn2 + nt * 16 + lr) * 40 + lq * 8];
            zl[nt] = *(const short8*)&Zcl[(wn2 + nt * 16 + lr) * 40 + lq * 8];
        }
#pragma unroll
        for (int mt = 0; mt < 2; ++mt)
#pragma unroll
            for (int nt = 0; nt < 2; ++nt) {
                acc2[mt][nt] = __builtin_amdgcn_mfma_f32_16x16x32_bf16(
                    ah[mt], zb[nt], acc2[mt][nt], 0, 0, 0);
                acc2[mt][nt] = __builtin_amdgcn_mfma_f32_16x16x32_bf16(
                    ah[mt], zl[nt], acc2[mt][nt], 0, 0, 0);
                acc2[mt][nt] = __builtin_amdgcn_mfma_f32_16x16x32_bf16(
                    al[mt], zb[nt], acc2[mt][nt], 0, 0, 0);
            }
    }
    __syncthreads();
    // write WtT [64][128] split into LDS
#pragma unroll
    for (int mt = 0; mt < 2; ++mt)
#pragma unroll
        for (int r4 = 0; r4 < 4; ++r4) {
            int row = wm2 + mt * 16 + lq * 4 + r4;
#pragma unroll
            for (int nt = 0; nt < 2; ++nt) {
                int col = wn2 + nt * 16 + lr;
                float v = acc2[mt][nt][r4];
                unsigned short hv = f2bf(v);
                Wh[row * WTPAD + col] = hv;
                Wl[row * WTPAD + col] = f2bf(v - bf2f(hv));
            }
        }
    __syncthreads();

    // ---------------- stage 3: hc^T[h][n] = Dinv[n]*sum_m W[h][m]*Hm[n][m]+cb
    int wn3 = wave * 64;
    floatx4 acc3[4][4] = {};
    for (int k0 = 0; k0 < M_; k0 += 32) {
        short8 ah[4], al[4], bh3[4];
#pragma unroll
        for (int nt = 0; nt < 4; ++nt)
            bh3[nt] = *(const short8*)&Hm[(long)(wn3 + nt * 16 + lr) * M_ + k0 + lq * 8];
#pragma unroll
        for (int mt = 0; mt < 4; ++mt) {
            ah[mt] = *(const short8*)&Wh[(mt * 16 + lr) * WTPAD + k0 + lq * 8];
            al[mt] = *(const short8*)&Wl[(mt * 16 + lr) * WTPAD + k0 + lq * 8];
        }
#pragma unroll
        for (int mt = 0; mt < 4; ++mt)
#pragma unroll
            for (int nt = 0; nt < 4; ++nt) {
                acc3[mt][nt] = __builtin_amdgcn_mfma_f32_16x16x32_bf16(
                    ah[mt], bh3[nt], acc3[mt][nt], 0, 0, 0);
                acc3[mt][nt] = __builtin_amdgcn_mfma_f32_16x16x32_bf16(
                    al[mt], bh3[nt], acc3[mt][nt], 0, 0, 0);
            }
    }

    float dv[4];
#pragma unroll
    for (int nt = 0; nt < 4; ++nt)
        dv[nt] = DinvN[b * N_ + wn3 + nt * 16 + lr];
    float cb[4][4];
#pragma unroll
    for (int mt = 0; mt < 4; ++mt)
#pragma unroll
        for (int r4 = 0; r4 < 4; ++r4)
            cb[mt][r4] = convb[h0 + mt * 16 + lq * 4 + r4];
#pragma unroll
    for (int mt = 0; mt < 4; ++mt)
#pragma unroll
        for (int nt = 0; nt < 4; ++nt)
#pragma unroll
            for (int r4 = 0; r4 < 4; ++r4)
                acc3[mt][nt][r4] = acc3[mt][nt][r4] * dv[nt] + cb[mt][r4];

    // BN stats over n: lane partials -> shuffle over lr -> LDS across waves
    float ps[4][4], pq[4][4];
#pragma unroll
    for (int mt = 0; mt < 4; ++mt)
#pragma unroll
        for (int r4 = 0; r4 < 4; ++r4) {
            float s = 0.f, q = 0.f;
#pragma unroll
            for (int nt = 0; nt < 4; ++nt) {
                float v = acc3[mt][nt][r4];
                s += v; q += v * v;
            }
            ps[mt][r4] = s; pq[mt][r4] = q;
        }
#pragma unroll
    for (int mask = 1; mask <= 8; mask <<= 1) {
#pragma unroll
        for (int mt = 0; mt < 4; ++mt)
#pragma unroll
            for (int r4 = 0; r4 < 4; ++r4) {
                ps[mt][r4] += __shfl_xor(ps[mt][r4], mask);
                pq[mt][r4] += __shfl_xor(pq[mt][r4], mask);
            }
    }
    if (lr == 0) {
#pragma unroll
        for (int mt = 0; mt < 4; ++mt)
#pragma unroll
            for (int r4 = 0; r4 < 4; ++r4) {
                int row = mt * 16 + lq * 4 + r4;
                rsum[row * 8 + wave] = ps[mt][r4];
                rsq[row * 8 + wave]  = pq[mt][r4];
            }
    }
    __syncthreads();
    if (tid < 64) {
        float s = 0.f, s2 = 0.f;
#pragma unroll
        for (int w = 0; w < 8; ++w) { s += rsum[tid * 8 + w]; s2 += rsq[tid * 8 + w]; }
        float mu  = s * (1.0f / N_);
        float var = fmaxf(s2 * (1.0f / N_) - mu * mu, 0.f);
        float sc  = gamma[h0 + tid] * rsqrtf(var + EPS_);
        prm[tid] = make_float2(sc, beta[h0 + tid] - mu * sc);
    }
    __syncthreads();

    unsigned short* ab = actOut + (long)b * H_ * N_;
#pragma unroll
    for (int mt = 0; mt < 4; ++mt)
#pragma unroll
        for (int r4 = 0; r4 < 4; ++r4) {
            int row = mt * 16 + lq * 4 + r4;
            float2 p = prm[row];
#pragma unroll
            for (int nt = 0; nt < 4; ++nt) {
                float y = fmaxf(acc3[mt][nt][r4] * p.x + p.y, 0.f);
                unsigned short hv = f2bf(y);
                long idx = (long)(h0 + row) * N_ + wn3 + nt * 16 + lr;
                ab[idx] = hv;
                ab[actLo + idx] = f2bf(y - bf2f(hv));
            }
        }
}

// ---- comb[n][h] = hT[h][n] + actT[h][n] (hi+lo), fp32 --------------------
__global__ __launch_bounds__(256) void comb_transpose_kernel(
    const unsigned short* __restrict__ actT, long actLo,
    const float* __restrict__ hT, float* __restrict__ comb)
{
    int b  = blockIdx.z;
    int n0 = blockIdx.x * 64, h0 = blockIdx.y * 64;
    __shared__ float tile[64][65];
    const unsigned short* ab = actT + (long)b * H_ * N_;
    const float* hb = hT + (long)b * H_ * N_;
    int x = threadIdx.x & 63, y0 = threadIdx.x >> 6;
#pragma unroll
    for (int i = 0; i < 16; ++i) {
        int y = y0 * 16 + i;
        long idx = (long)(h0 + y) * N_ + n0 + x;
        tile[y][x] = bf2f(ab[idx]) + bf2f(ab[actLo + idx]) + hb[idx];
    }
    __syncthreads();
#pragma unroll
    for (int i = 0; i < 16; ++i) {
        int y = y0 * 16 + i;
        comb[((long)b * N_ + n0 + y) * H_ + h0 + x] = tile[x][y];
    }
}

// -------------------- fp32 tiled GEMM (decoder only) ----------------------
__global__ __launch_bounds__(256) void gemm_kernel(
    const float* __restrict__ A, long aStride,
    const float* __restrict__ Bm, long bStride,
    float* __restrict__ C, long cStride,
    int M, int Nn, int K,
    const float* __restrict__ bias)
{
    int b  = blockIdx.z;
    int m0 = blockIdx.y * TILE;
    int n0 = blockIdx.x * TILE;
    const float* Ab = A + (long)b * aStride;
    const float* Bb = Bm + (long)b * bStride;
    float*       Cb = C + (long)b * cStride;

    __shared__ float As[KC][TILE];
    __shared__ float Bs[KC][TILE];

    int tid = threadIdx.x;
    int tx4 = (tid & 15) << 2;
    int ty4 = (tid >> 4) << 2;
    int lr  = tid >> 2;
    int lc4 = (tid & 3) << 2;
    int br  = tid >> 4;
    int bc4 = (tid & 15) << 2;

    float acc[4][4] = {};

    for (int k0 = 0; k0 < K; k0 += KC) {
        float4 av = *(const float4*)(Ab + (long)(m0 + lr) * K + k0 + lc4);
        As[lc4 + 0][lr] = av.x;
        As[lc4 + 1][lr] = av.y;
        As[lc4 + 2][lr] = av.z;
        As[lc4 + 3][lr] = av.w;
        int cc = n0 + bc4;
        float4 bv = make_float4(0.f, 0.f, 0.f, 0.f);
        const float* bp = Bb + (long)(k0 + br) * Nn + cc;
        if (cc + 3 < Nn) {
            bv = *(const float4*)bp;
        } else {
            if (cc + 0 < Nn) bv.x = bp[0];
            if (cc + 1 < Nn) bv.y = bp[1];
            if (cc + 2 < Nn) bv.z = bp[2];
            if (cc + 3 < Nn) bv.w = bp[3];
        }
        *(float4*)&Bs[br][bc4] = bv;
        __syncthreads();
#pragma unroll
        for (int kk = 0; kk < KC; ++kk) {
            float4 a  = *(const float4*)&As[kk][ty4];
            float4 bq = *(const float4*)&Bs[kk][tx4];
            acc[0][0] += a.x * bq.x; acc[0][1] += a.x * bq.y;
            acc[0][2] += a.x * bq.z; acc[0][3] += a.x * bq.w;
            acc[1][0] += a.y * bq.x; acc[1][1] += a.y * bq.y;
            acc[1][2] += a.y * bq.z; acc[1][3] += a.y * bq.w;
            acc[2][0] += a.z * bq.x; acc[2][1] += a.z * bq.y;
            acc[2][2] += a.z * bq.z; acc[2][3] += a.z * bq.w;
            acc[3][0] += a.w * bq.x; acc[3][1] += a.w * bq.y;
            acc[3][2] += a.w * bq.z; acc[3][3] += a.w * bq.w;
        }
        __syncthreads();
    }

#pragma unroll
    for (int i = 0; i < 4; ++i) {
        int r = m0 + ty4 + i;
#pragma unroll
        for (int j = 0; j < 4; ++j) {
            int c = n0 + tx4 + j;
            if (c < Nn)
                Cb[(long)r * Nn + c] = acc[i][j] + (bias ? bias[c] : 0.f);
        }
    }
}

// --------------------------------------------------------------------------
extern "C" void kernel_launch(void* const* d_in, const int* in_sizes, int n_in,
                              void* d_out, int out_size, void* d_ws, size_t ws_size,
                              hipStream_t stream) {
    const float* obs    = (const float*)d_in[0];
    const int*   hyper  = (const int*)d_in[1];
    const float* Wenc   = (const float*)d_in[2];
    const float* benc   = (const float*)d_in[3];
    const float* thetas = (const float*)d_in[4];
    const float* convb  = (const float*)d_in[5];
    const float* gammas = (const float*)d_in[6];
    const float* betas  = (const float*)d_in[7];
    const float* Wdec   = (const float*)d_in[8];
    const float* bdec   = (const float*)d_in[9];
    float* out = (float*)d_out;

    char* w = (char*)d_ws;
    auto alloc = [&](size_t bytes) { char* p = w; w += (bytes + 255) & ~255ULL; return p; };
    float* hT    = (float*)alloc((size_t)B_ * H_ * N_ * 4);
    float* comb  = (float*)alloc((size_t)B_ * N_ * H_ * 4);
    float* DinvN = (float*)alloc((size_t)B_ * N_ * 4);
    float* BinvM = (float*)alloc((size_t)B_ * M_ * 4);
    unsigned short* Hmat  = (unsigned short*)alloc((size_t)B_ * N_ * M_ * 2);
    unsigned short* HmatT = (unsigned short*)alloc((size_t)B_ * M_ * N_ * 2);
    unsigned short* actA  = (unsigned short*)alloc((size_t)B_ * H_ * N_ * 2 * 2);
    unsigned short* actB  = (unsigned short*)alloc((size_t)B_ * H_ * N_ * 2 * 2);
    unsigned short* thT   = (unsigned short*)alloc((size_t)L_ * H_ * H_ * 2 * 2);

    const long actLo = (long)B_ * H_ * N_;
    const long thLo  = (long)L_ * H_ * H_;

    hipMemsetAsync(BinvM, 0, (size_t)B_ * M_ * 4, stream);
    encoder2_kernel<<<dim3(B_, 4), 512, 0, stream>>>(obs, Wenc, benc, hT, actA, actLo);
    build_kernel<<<dim3(B_, 8), 256, 0, stream>>>(hyper, Hmat, HmatT, DinvN, BinvM);
    inv_kernel<<<(B_ * M_ + 255) / 256, 256, 0, stream>>>(BinvM, B_ * M_);
    transpose_f32_bf16split<<<dim3(4, 4, 3), 256, 0, stream>>>(
        thetas, (long)H_ * H_, thT, (long)H_ * H_, thLo, H_, H_);

    const unsigned short* cur = actA;
    unsigned short* nxt = actB;
    for (int l = 0; l < L_; ++l) {
        layer_kernel<<<dim3(4, B_), 512, 0, stream>>>(
            HmatT, Hmat, cur, actLo, thT + (size_t)l * H_ * H_, thLo,
            BinvM, DinvN, convb + (size_t)l * H_,
            gammas + (size_t)l * H_, betas + (size_t)l * H_, nxt);
        const unsigned short* t = cur; cur = nxt; nxt = (unsigned short*)t;
    }
    // comb = h + h_social  (cur holds final activations)
    comb_transpose_kernel<<<dim3(8, 4, B_), 256, 0, stream>>>(cur, actLo, hT, comb);
    // out = comb @ Wdec + bdec (fp32)
    gemm_kernel<<<dim3(1, N_ / TILE, B_), 256, 0, stream>>>(
        comb, (long)N_ * H_, Wdec, 0,
        out, (long)N_ * P2_, N_, P2_, H_, bdec);
}

// Round 6
// 421.332 us; speedup vs baseline: 1.0784x; 1.0784x over previous
//
#include <hip/hip_runtime.h>
#include <hip/hip_bf16.h>

#define B_   64
#define N_   512
#define T_   8
#define DIN_ 2
#define H_   256
#define L_   3
#define E_   8192
#define M_   128
#define P2_  24   // P*2
#define EPS_ 1e-5f

#define TILE 64
#define KC   16
#define WTPAD 136

typedef __attribute__((ext_vector_type(8))) short short8;
typedef __attribute__((ext_vector_type(4))) float floatx4;

__device__ __forceinline__ unsigned short f2bf(float f) {
    union { float f; unsigned u; } v; v.f = f;
    unsigned r = v.u + 0x7FFF + ((v.u >> 16) & 1);
    return (unsigned short)(r >> 16);
}
__device__ __forceinline__ float bf2f(unsigned short h) {
    union { unsigned u; float f; } v; v.u = (unsigned)h << 16; return v.f;
}

// ---- encoder: hT[b,c,n] fp32 + actT[b,c,n] split bf16 (mean_t relu) ------
// wave owns row c (wave-uniform weights); lane owns n = j*64+lane -> all
// global writes coalesced. LDS obs staged at stride 17 (odd) -> conflict-free.
__global__ __launch_bounds__(512) void encoder2_kernel(
    const float* __restrict__ obs, const float* __restrict__ Wenc,
    const float* __restrict__ benc, float* __restrict__ hT,
    unsigned short* __restrict__ actT, long actLo)
{
    int b = blockIdx.x, h0 = blockIdx.y * 64;
    __shared__ float o[512 * 17];
    const float4* src = (const float4*)(obs + (long)b * N_ * 16);
    int tid = threadIdx.x;
    for (int i = tid; i < 2048; i += 512) {
        int n = i >> 2, k = (i & 3) << 2;
        float4 v = src[i];
        float* dst = &o[n * 17 + k];
        dst[0] = v.x; dst[1] = v.y; dst[2] = v.z; dst[3] = v.w;
    }
    __syncthreads();
    int wave = tid >> 6, lane = tid & 63;
#pragma unroll
    for (int i = 0; i < 8; ++i) {
        int c = h0 + wave * 8 + i;                 // wave-uniform
        float w0 = Wenc[c], w1 = Wenc[H_ + c], bb = benc[c];
        long rowbase = ((long)b * H_ + c) * N_;
#pragma unroll
        for (int j = 0; j < 8; ++j) {
            int n = j * 64 + lane;                 // lane-consecutive
            const float* op = &o[n * 17];
            float acc = 0.f;
#pragma unroll
            for (int t = 0; t < T_; ++t) {
                float v = op[2 * t] * w0 + op[2 * t + 1] * w1 + bb;
                acc += fmaxf(v, 0.f);
            }
            acc *= 0.125f;
            long idx = rowbase + n;
            hT[idx] = acc;
            unsigned short hv = f2bf(acc);
            actT[idx] = hv;
            actT[actLo + idx] = f2bf(acc - bf2f(hv));
        }
    }
}

// -------------------- densify incidence via LDS counts --------------------
__global__ __launch_bounds__(256) void build_kernel(const int* __restrict__ idx,
    unsigned short* __restrict__ Hmat, unsigned short* __restrict__ HmatT,
    float* __restrict__ DinvN, float* __restrict__ degM)
{
    int b = blockIdx.x;
    int chunk = blockIdx.y;
    int c0 = chunk * 64;
    __shared__ unsigned int cnt[64 * 129];
    for (int i = threadIdx.x; i < 64 * 129; i += 256) cnt[i] = 0;
    __syncthreads();
    const int* nodes = idx + (long)b * 2 * E_;
    const int* edges = nodes + E_;
    for (int e = threadIdx.x; e < E_; e += 256) {
        int n = nodes[e];
        if ((n >> 6) == chunk) {
            int m = edges[e];
            atomicAdd(&cnt[(n & 63) * 129 + m], 1u);
        }
    }
    __syncthreads();
    for (int i = threadIdx.x; i < 64 * 128; i += 256) {
        int r = i >> 7, m = i & 127;
        Hmat[((long)(b * N_ + c0 + r)) * M_ + m] = f2bf((float)cnt[r * 129 + m]);
    }
    for (int i = threadIdx.x; i < 64 * 128; i += 256) {
        int m = i >> 6, r = i & 63;
        HmatT[((long)(b * M_ + m)) * N_ + c0 + r] = f2bf((float)cnt[r * 129 + m]);
    }
    if (threadIdx.x < 64) {
        int r = threadIdx.x;
        unsigned s = 0;
#pragma unroll 8
        for (int m = 0; m < 128; ++m) s += cnt[r * 129 + m];
        DinvN[b * N_ + c0 + r] = 1.0f / fmaxf((float)s, 1.0f);
    } else if (threadIdx.x < 192) {
        int m = threadIdx.x - 64;
        unsigned s = 0;
#pragma unroll 8
        for (int r = 0; r < 64; ++r) s += cnt[r * 129 + m];
        atomicAdd(&degM[b * M_ + m], (float)s);
    }
}

__global__ void inv_kernel(float* deg, int n) {
    int i = blockIdx.x * blockDim.x + threadIdx.x;
    if (i < n) deg[i] = 1.0f / fmaxf(deg[i], 1.0f);
}

// ---------- fp32 [R,C] -> SPLIT bf16 [C,R] batched transpose (thetas) -----
__global__ __launch_bounds__(256) void transpose_f32_bf16split(
    const float* __restrict__ in, long inStride,
    unsigned short* __restrict__ outT, long outStride, long loOff, int R, int C)
{
    int b = blockIdx.z;
    int r0 = blockIdx.y * 64, c0 = blockIdx.x * 64;
    __shared__ float tile[64][65];
    const float* ib = in + (long)b * inStride;
    unsigned short* ob = outT + (long)b * outStride;
    int x = threadIdx.x & 63;
    int y0 = threadIdx.x >> 6;
#pragma unroll
    for (int i = 0; i < 16; ++i) {
        int y = y0 * 16 + i;
        tile[y][x] = ib[(long)(r0 + y) * C + c0 + x];
    }
    __syncthreads();
#pragma unroll
    for (int i = 0; i < 16; ++i) {
        int y = y0 * 16 + i;
        float v = tile[x][y];
        unsigned short hv = f2bf(v);
        long idx = (long)(c0 + y) * R + r0 + x;
        ob[idx] = hv;
        ob[loOff + idx] = f2bf(v - bf2f(hv));
    }
}

// ======== fused layer: Z=Binv(H^T X) ; W=Theta^T Z^T ; hc^T=Dinv(W Hm^T)+b ;
//          BN over n ; ReLU ; write split actOut.  1 block = (batch, 64 h-rows)
__global__ __launch_bounds__(512, 2) void layer_kernel(
    const unsigned short* __restrict__ HmatT,   // [B][128][512]
    const unsigned short* __restrict__ Hmat,    // [B][512][128]
    const unsigned short* __restrict__ actIn, long actLo,
    const unsigned short* __restrict__ thT, long thLo,  // pre-offset to layer
    const float* __restrict__ BinvM, const float* __restrict__ DinvN,
    const float* __restrict__ convb, const float* __restrict__ gamma,
    const float* __restrict__ beta,
    unsigned short* __restrict__ actOut)
{
    __shared__ __align__(16) char lds[51200];
    unsigned short* As1  = (unsigned short*)lds;            // [128][40]
    unsigned short* Bs1h = As1 + 128 * 40;                  // [256][40]
    unsigned short* Bs1l = Bs1h + 256 * 40;                 // [256][40]
    unsigned short* Zch  = (unsigned short*)lds;            // [128][40]
    unsigned short* Zcl  = Zch + 128 * 40;
    unsigned short* As2h = Zcl + 128 * 40;                  // [64][40]
    unsigned short* As2l = As2h + 64 * 40;
    unsigned short* Wh   = (unsigned short*)lds;            // [64][136]
    unsigned short* Wl   = Wh + 64 * WTPAD;
    float* rsum = (float*)(lds + 64 * WTPAD * 2 * 2);       // [64][8]
    float* rsq  = rsum + 512;
    float2* prm = (float2*)(rsq + 512);                     // [64]

    int b = blockIdx.y, h0 = blockIdx.x * 64;
    int tid = threadIdx.x, wave = tid >> 6, lane = tid & 63;
    int lr = lane & 15, lq = lane >> 4;

    const unsigned short* HT  = HmatT + (long)b * M_ * N_;
    const unsigned short* Hm  = Hmat + (long)b * N_ * M_;
    const unsigned short* aIn = actIn + (long)b * H_ * N_;

    // ---------------- stage 1: Z[m][h'] = Binv[m] * sum_n HT[m][n]*act[h'][n]
    int wm1 = (wave >> 2) * 64;
    int wn1 = (wave & 3) * 64;
    floatx4 acc1[4][4] = {};
    for (int k0 = 0; k0 < N_; k0 += 32) {
        __syncthreads();
        {
            int r = tid >> 2, ck = (tid & 3) << 3;
            *(uint4*)&As1[r * 40 + ck] = *(const uint4*)&HT[(long)r * N_ + k0 + ck];
        }
#pragma unroll
        for (int i = tid; i < 1024; i += 512) {
            int r = i >> 2, ck = (i & 3) << 3;
            *(uint4*)&Bs1h[r * 40 + ck] = *(const uint4*)&aIn[(long)r * N_ + k0 + ck];
            *(uint4*)&Bs1l[r * 40 + ck] = *(const uint4*)&aIn[actLo + (long)r * N_ + k0 + ck];
        }
        __syncthreads();
        short8 af[4], bh[4], bl[4];
#pragma unroll
        for (int mt = 0; mt < 4; ++mt)
            af[mt] = *(const short8*)&As1[(wm1 + mt * 16 + lr) * 40 + lq * 8];
#pragma unroll
        for (int nt = 0; nt < 4; ++nt) {
            bh[nt] = *(const short8*)&Bs1h[(wn1 + nt * 16 + lr) * 40 + lq * 8];
            bl[nt] = *(const short8*)&Bs1l[(wn1 + nt * 16 + lr) * 40 + lq * 8];
        }
#pragma unroll
        for (int mt = 0; mt < 4; ++mt)
#pragma unroll
            for (int nt = 0; nt < 4; ++nt) {
                acc1[mt][nt] = __builtin_amdgcn_mfma_f32_16x16x32_bf16(
                    af[mt], bh[nt], acc1[mt][nt], 0, 0, 0);
                acc1[mt][nt] = __builtin_amdgcn_mfma_f32_16x16x32_bf16(
                    af[mt], bl[nt], acc1[mt][nt], 0, 0, 0);
            }
    }
    float rsB[4][4];
#pragma unroll
    for (int mt = 0; mt < 4; ++mt)
#pragma unroll
        for (int r4 = 0; r4 < 4; ++r4)
            rsB[mt][r4] = BinvM[b * M_ + wm1 + mt * 16 + lq * 4 + r4];

    // ---------------- stage 2: W[h][m] = sum_h' thT[h][h'] * Z[m][h']
    int wm2 = (wave >> 2) * 32, wn2 = (wave & 3) * 32;
    floatx4 acc2[2][2] = {};
    for (int k0 = 0; k0 < H_; k0 += 32) {
        __syncthreads();
        if ((wave & 3) == (k0 >> 6)) {
            int nt0 = (k0 >> 4) & 2;
#pragma unroll
            for (int ntl = 0; ntl < 4; ++ntl) {
                if ((ntl & 2) == nt0) {
                    int kk = ((ntl & 1) << 4) + lr;
#pragma unroll
                    for (int mtl = 0; mtl < 4; ++mtl)
#pragma unroll
                        for (int r4 = 0; r4 < 4; ++r4) {
                            int m = wm1 + mtl * 16 + lq * 4 + r4;
                            float v = acc1[mtl][ntl][r4] * rsB[mtl][r4];
                            unsigned short hv = f2bf(v);
                            Zch[m * 40 + kk] = hv;
                            Zcl[m * 40 + kk] = f2bf(v - bf2f(hv));
                        }
                }
            }
        }
        {
            int i = tid & 255, pl = tid >> 8;
            int r = i >> 2, ck = (i & 3) << 3;
            const unsigned short* src = thT + (pl ? thLo : 0) + (long)(h0 + r) * H_ + k0 + ck;
            *(uint4*)((pl ? As2l : As2h) + r * 40 + ck) = *(const uint4*)src;
        }
        __syncthreads();
        short8 ah[2], al[2], zb[2], zl[2];
#pragma unroll
        for (int mt = 0; mt < 2; ++mt) {
            ah[mt] = *(const short8*)&As2h[(wm2 + mt * 16 + lr) * 40 + lq * 8];
            al[mt] = *(const short8*)&As2l[(wm2 + mt * 16 + lr) * 40 + lq * 8];
        }
#pragma unroll
        for (int nt = 0; nt < 2; ++nt) {
            zb[nt] = *(const short8*)&Zch[(wn2 + nt * 16 + lr) * 40 + lq * 8];
            zl[nt] = *(const short8*)&Zcl[(wn2 + nt * 16 + lr) * 40 + lq * 8];
        }
#pragma unroll
        for (int mt = 0; mt < 2; ++mt)
#pragma unroll
            for (int nt = 0; nt < 2; ++nt) {
                acc2[mt][nt] = __builtin_amdgcn_mfma_f32_16x16x32_bf16(
                    ah[mt], zb[nt], acc2[mt][nt], 0, 0, 0);
                acc2[mt][nt] = __builtin_amdgcn_mfma_f32_16x16x32_bf16(
                    ah[mt], zl[nt], acc2[mt][nt], 0, 0, 0);
                acc2[mt][nt] = __builtin_amdgcn_mfma_f32_16x16x32_bf16(
                    al[mt], zb[nt], acc2[mt][nt], 0, 0, 0);
            }
    }
    __syncthreads();
#pragma unroll
    for (int mt = 0; mt < 2; ++mt)
#pragma unroll
        for (int r4 = 0; r4 < 4; ++r4) {
            int row = wm2 + mt * 16 + lq * 4 + r4;
#pragma unroll
            for (int nt = 0; nt < 2; ++nt) {
                int col = wn2 + nt * 16 + lr;
                float v = acc2[mt][nt][r4];
                unsigned short hv = f2bf(v);
                Wh[row * WTPAD + col] = hv;
                Wl[row * WTPAD + col] = f2bf(v - bf2f(hv));
            }
        }
    __syncthreads();

    // ---------------- stage 3: hc^T[h][n] = Dinv[n]*sum_m W[h][m]*Hm[n][m]+cb
    int wn3 = wave * 64;
    floatx4 acc3[4][4] = {};
    for (int k0 = 0; k0 < M_; k0 += 32) {
        short8 ah[4], al[4], bh3[4];
#pragma unroll
        for (int nt = 0; nt < 4; ++nt)
            bh3[nt] = *(const short8*)&Hm[(long)(wn3 + nt * 16 + lr) * M_ + k0 + lq * 8];
#pragma unroll
        for (int mt = 0; mt < 4; ++mt) {
            ah[mt] = *(const short8*)&Wh[(mt * 16 + lr) * WTPAD + k0 + lq * 8];
            al[mt] = *(const short8*)&Wl[(mt * 16 + lr) * WTPAD + k0 + lq * 8];
        }
#pragma unroll
        for (int mt = 0; mt < 4; ++mt)
#pragma unroll
            for (int nt = 0; nt < 4; ++nt) {
                acc3[mt][nt] = __builtin_amdgcn_mfma_f32_16x16x32_bf16(
                    ah[mt], bh3[nt], acc3[mt][nt], 0, 0, 0);
                acc3[mt][nt] = __builtin_amdgcn_mfma_f32_16x16x32_bf16(
                    al[mt], bh3[nt], acc3[mt][nt], 0, 0, 0);
            }
    }

    float dv[4];
#pragma unroll
    for (int nt = 0; nt < 4; ++nt)
        dv[nt] = DinvN[b * N_ + wn3 + nt * 16 + lr];
    float cb[4][4];
#pragma unroll
    for (int mt = 0; mt < 4; ++mt)
#pragma unroll
        for (int r4 = 0; r4 < 4; ++r4)
            cb[mt][r4] = convb[h0 + mt * 16 + lq * 4 + r4];
#pragma unroll
    for (int mt = 0; mt < 4; ++mt)
#pragma unroll
        for (int nt = 0; nt < 4; ++nt)
#pragma unroll
            for (int r4 = 0; r4 < 4; ++r4)
                acc3[mt][nt][r4] = acc3[mt][nt][r4] * dv[nt] + cb[mt][r4];

    float ps[4][4], pq[4][4];
#pragma unroll
    for (int mt = 0; mt < 4; ++mt)
#pragma unroll
        for (int r4 = 0; r4 < 4; ++r4) {
            float s = 0.f, q = 0.f;
#pragma unroll
            for (int nt = 0; nt < 4; ++nt) {
                float v = acc3[mt][nt][r4];
                s += v; q += v * v;
            }
            ps[mt][r4] = s; pq[mt][r4] = q;
        }
#pragma unroll
    for (int mask = 1; mask <= 8; mask <<= 1) {
#pragma unroll
        for (int mt = 0; mt < 4; ++mt)
#pragma unroll
            for (int r4 = 0; r4 < 4; ++r4) {
                ps[mt][r4] += __shfl_xor(ps[mt][r4], mask);
                pq[mt][r4] += __shfl_xor(pq[mt][r4], mask);
            }
    }
    if (lr == 0) {
#pragma unroll
        for (int mt = 0; mt < 4; ++mt)
#pragma unroll
            for (int r4 = 0; r4 < 4; ++r4) {
                int row = mt * 16 + lq * 4 + r4;
                rsum[row * 8 + wave] = ps[mt][r4];
                rsq[row * 8 + wave]  = pq[mt][r4];
            }
    }
    __syncthreads();
    if (tid < 64) {
        float s = 0.f, s2 = 0.f;
#pragma unroll
        for (int w = 0; w < 8; ++w) { s += rsum[tid * 8 + w]; s2 += rsq[tid * 8 + w]; }
        float mu  = s * (1.0f / N_);
        float var = fmaxf(s2 * (1.0f / N_) - mu * mu, 0.f);
        float sc  = gamma[h0 + tid] * rsqrtf(var + EPS_);
        prm[tid] = make_float2(sc, beta[h0 + tid] - mu * sc);
    }
    __syncthreads();

    unsigned short* ab = actOut + (long)b * H_ * N_;
#pragma unroll
    for (int mt = 0; mt < 4; ++mt)
#pragma unroll
        for (int r4 = 0; r4 < 4; ++r4) {
            int row = mt * 16 + lq * 4 + r4;
            float2 p = prm[row];
#pragma unroll
            for (int nt = 0; nt < 4; ++nt) {
                float y = fmaxf(acc3[mt][nt][r4] * p.x + p.y, 0.f);
                unsigned short hv = f2bf(y);
                long idx = (long)(h0 + row) * N_ + wn3 + nt * 16 + lr;
                ab[idx] = hv;
                ab[actLo + idx] = f2bf(y - bf2f(hv));
            }
        }
}

// ---- comb[n][h] = hT[h][n] + actT[h][n] (hi+lo), fp32 --------------------
__global__ __launch_bounds__(256) void comb_transpose_kernel(
    const unsigned short* __restrict__ actT, long actLo,
    const float* __restrict__ hT, float* __restrict__ comb)
{
    int b  = blockIdx.z;
    int n0 = blockIdx.x * 64, h0 = blockIdx.y * 64;
    __shared__ float tile[64][65];
    const unsigned short* ab = actT + (long)b * H_ * N_;
    const float* hb = hT + (long)b * H_ * N_;
    int x = threadIdx.x & 63, y0 = threadIdx.x >> 6;
#pragma unroll
    for (int i = 0; i < 16; ++i) {
        int y = y0 * 16 + i;
        long idx = (long)(h0 + y) * N_ + n0 + x;
        tile[y][x] = bf2f(ab[idx]) + bf2f(ab[actLo + idx]) + hb[idx];
    }
    __syncthreads();
#pragma unroll
    for (int i = 0; i < 16; ++i) {
        int y = y0 * 16 + i;
        comb[((long)b * N_ + n0 + y) * H_ + h0 + x] = tile[x][y];
    }
}

// -------------------- fp32 tiled GEMM (decoder only) ----------------------
__global__ __launch_bounds__(256) void gemm_kernel(
    const float* __restrict__ A, long aStride,
    const float* __restrict__ Bm, long bStride,
    float* __restrict__ C, long cStride,
    int M, int Nn, int K,
    const float* __restrict__ bias)
{
    int b  = blockIdx.z;
    int m0 = blockIdx.y * TILE;
    int n0 = blockIdx.x * TILE;
    const float* Ab = A + (long)b * aStride;
    const float* Bb = Bm + (long)b * bStride;
    float*       Cb = C + (long)b * cStride;

    __shared__ float As[KC][TILE];
    __shared__ float Bs[KC][TILE];

    int tid = threadIdx.x;
    int tx4 = (tid & 15) << 2;
    int ty4 = (tid >> 4) << 2;
    int lr  = tid >> 2;
    int lc4 = (tid & 3) << 2;
    int br  = tid >> 4;
    int bc4 = (tid & 15) << 2;

    float acc[4][4] = {};

    for (int k0 = 0; k0 < K; k0 += KC) {
        float4 av = *(const float4*)(Ab + (long)(m0 + lr) * K + k0 + lc4);
        As[lc4 + 0][lr] = av.x;
        As[lc4 + 1][lr] = av.y;
        As[lc4 + 2][lr] = av.z;
        As[lc4 + 3][lr] = av.w;
        int cc = n0 + bc4;
        float4 bv = make_float4(0.f, 0.f, 0.f, 0.f);
        const float* bp = Bb + (long)(k0 + br) * Nn + cc;
        if (cc + 3 < Nn) {
            bv = *(const float4*)bp;
        } else {
            if (cc + 0 < Nn) bv.x = bp[0];
            if (cc + 1 < Nn) bv.y = bp[1];
            if (cc + 2 < Nn) bv.z = bp[2];
            if (cc + 3 < Nn) bv.w = bp[3];
        }
        *(float4*)&Bs[br][bc4] = bv;
        __syncthreads();
#pragma unroll
        for (int kk = 0; kk < KC; ++kk) {
            float4 a  = *(const float4*)&As[kk][ty4];
            float4 bq = *(const float4*)&Bs[kk][tx4];
            acc[0][0] += a.x * bq.x; acc[0][1] += a.x * bq.y;
            acc[0][2] += a.x * bq.z; acc[0][3] += a.x * bq.w;
            acc[1][0] += a.y * bq.x; acc[1][1] += a.y * bq.y;
            acc[1][2] += a.y * bq.z; acc[1][3] += a.y * bq.w;
            acc[2][0] += a.z * bq.x; acc[2][1] += a.z * bq.y;
            acc[2][2] += a.z * bq.z; acc[2][3] += a.z * bq.w;
            acc[3][0] += a.w * bq.x; acc[3][1] += a.w * bq.y;
            acc[3][2] += a.w * bq.z; acc[3][3] += a.w * bq.w;
        }
        __syncthreads();
    }

#pragma unroll
    for (int i = 0; i < 4; ++i) {
        int r = m0 + ty4 + i;
#pragma unroll
        for (int j = 0; j < 4; ++j) {
            int c = n0 + tx4 + j;
            if (c < Nn)
                Cb[(long)r * Nn + c] = acc[i][j] + (bias ? bias[c] : 0.f);
        }
    }
}

// --------------------------------------------------------------------------
extern "C" void kernel_launch(void* const* d_in, const int* in_sizes, int n_in,
                              void* d_out, int out_size, void* d_ws, size_t ws_size,
                              hipStream_t stream) {
    const float* obs    = (const float*)d_in[0];
    const int*   hyper  = (const int*)d_in[1];
    const float* Wenc   = (const float*)d_in[2];
    const float* benc   = (const float*)d_in[3];
    const float* thetas = (const float*)d_in[4];
    const float* convb  = (const float*)d_in[5];
    const float* gammas = (const float*)d_in[6];
    const float* betas  = (const float*)d_in[7];
    const float* Wdec   = (const float*)d_in[8];
    const float* bdec   = (const float*)d_in[9];
    float* out = (float*)d_out;

    char* w = (char*)d_ws;
    auto alloc = [&](size_t bytes) { char* p = w; w += (bytes + 255) & ~255ULL; return p; };
    float* hT    = (float*)alloc((size_t)B_ * H_ * N_ * 4);
    float* comb  = (float*)alloc((size_t)B_ * N_ * H_ * 4);
    float* DinvN = (float*)alloc((size_t)B_ * N_ * 4);
    float* BinvM = (float*)alloc((size_t)B_ * M_ * 4);
    unsigned short* Hmat  = (unsigned short*)alloc((size_t)B_ * N_ * M_ * 2);
    unsigned short* HmatT = (unsigned short*)alloc((size_t)B_ * M_ * N_ * 2);
    unsigned short* actA  = (unsigned short*)alloc((size_t)B_ * H_ * N_ * 2 * 2);
    unsigned short* actB  = (unsigned short*)alloc((size_t)B_ * H_ * N_ * 2 * 2);
    unsigned short* thT   = (unsigned short*)alloc((size_t)L_ * H_ * H_ * 2 * 2);

    const long actLo = (long)B_ * H_ * N_;
    const long thLo  = (long)L_ * H_ * H_;

    hipMemsetAsync(BinvM, 0, (size_t)B_ * M_ * 4, stream);
    encoder2_kernel<<<dim3(B_, 4), 512, 0, stream>>>(obs, Wenc, benc, hT, actA, actLo);
    build_kernel<<<dim3(B_, 8), 256, 0, stream>>>(hyper, Hmat, HmatT, DinvN, BinvM);
    inv_kernel<<<(B_ * M_ + 255) / 256, 256, 0, stream>>>(BinvM, B_ * M_);
    transpose_f32_bf16split<<<dim3(4, 4, 3), 256, 0, stream>>>(
        thetas, (long)H_ * H_, thT, (long)H_ * H_, thLo, H_, H_);

    const unsigned short* cur = actA;
    unsigned short* nxt = actB;
    for (int l = 0; l < L_; ++l) {
        layer_kernel<<<dim3(4, B_), 512, 0, stream>>>(
            HmatT, Hmat, cur, actLo, thT + (size_t)l * H_ * H_, thLo,
            BinvM, DinvN, convb + (size_t)l * H_,
            gammas + (size_t)l * H_, betas + (size_t)l * H_, nxt);
        const unsigned short* t = cur; cur = nxt; nxt = (unsigned short*)t;
    }
    // comb = h + h_social  (cur holds final activations)
    comb_transpose_kernel<<<dim3(8, 4, B_), 256, 0, stream>>>(cur, actLo, hT, comb);
    // out = comb @ Wdec + bdec (fp32)
    gemm_kernel<<<dim3(1, N_ / TILE, B_), 256, 0, stream>>>(
        comb, (long)N_ * H_, Wdec, 0,
        out, (long)N_ * P2_, N_, P2_, H_, bdec);
}

// Round 7
// 335.501 us; speedup vs baseline: 1.3543x; 1.2558x over previous
//
#include <hip/hip_runtime.h>
#include <hip/hip_bf16.h>

#define B_   64
#define N_   512
#define T_   8
#define DIN_ 2
#define H_   256
#define L_   3
#define E_   8192
#define M_   128
#define P2_  24   // P*2
#define EPS_ 1e-5f

#define TILE 64
#define KC   16
#define WTPAD 136

typedef __attribute__((ext_vector_type(8))) short short8;
typedef __attribute__((ext_vector_type(4))) float floatx4;

__device__ __forceinline__ unsigned short f2bf(float f) {
    union { float f; unsigned u; } v; v.f = f;
    unsigned r = v.u + 0x7FFF + ((v.u >> 16) & 1);
    return (unsigned short)(r >> 16);
}
__device__ __forceinline__ float bf2f(unsigned short h) {
    union { unsigned u; float f; } v; v.u = (unsigned)h << 16; return v.f;
}

// ---- encoder: hT[b,c,n] fp32 + actT[b,c,n] split bf16 (mean_t relu) ------
// obs staged TRANSPOSED in LDS (ot[16][513], conflict-free b32 reads).
// Each thread loads its n-row's 16 values once per j, reuses across 8 c.
__global__ __launch_bounds__(512, 4) void encoder3_kernel(
    const float* __restrict__ obs, const float* __restrict__ Wenc,
    const float* __restrict__ benc, float* __restrict__ hT,
    unsigned short* __restrict__ actT, long actLo)
{
    int b = blockIdx.x, h0 = blockIdx.y * 64;
    __shared__ float ot[16 * 513];
    const float4* src = (const float4*)(obs + (long)b * N_ * 16);
    int tid = threadIdx.x;
    for (int i = tid; i < 2048; i += 512) {
        float4 v = src[i];
        int n = i >> 2, k4 = (i & 3) << 2;
        ot[(k4 + 0) * 513 + n] = v.x;
        ot[(k4 + 1) * 513 + n] = v.y;
        ot[(k4 + 2) * 513 + n] = v.z;
        ot[(k4 + 3) * 513 + n] = v.w;
    }
    __syncthreads();
    int wave = tid >> 6, lane = tid & 63;
    int cbase = h0 + wave * 8;
    float w0[8], w1[8], bb[8];
#pragma unroll
    for (int i = 0; i < 8; ++i) {
        w0[i] = Wenc[cbase + i];
        w1[i] = Wenc[H_ + cbase + i];
        bb[i] = benc[cbase + i];
    }
    for (int j = 0; j < 8; ++j) {
        int n = j * 64 + lane;
        float x0[8], x1[8];
#pragma unroll
        for (int t = 0; t < 8; ++t) {
            x0[t] = ot[(2 * t) * 513 + n];
            x1[t] = ot[(2 * t + 1) * 513 + n];
        }
#pragma unroll
        for (int i = 0; i < 8; ++i) {
            float acc = 0.f;
#pragma unroll
            for (int t = 0; t < 8; ++t)
                acc += fmaxf(x0[t] * w0[i] + x1[t] * w1[i] + bb[i], 0.f);
            acc *= 0.125f;
            long idx = ((long)b * H_ + cbase + i) * N_ + n;
            hT[idx] = acc;
            unsigned short hv = f2bf(acc);
            actT[idx] = hv;
            actT[actLo + idx] = f2bf(acc - bf2f(hv));
        }
    }
}

// -------------------- densify incidence via LDS counts --------------------
__global__ __launch_bounds__(256) void build_kernel(const int* __restrict__ idx,
    unsigned short* __restrict__ Hmat, unsigned short* __restrict__ HmatT,
    float* __restrict__ DinvN, float* __restrict__ degM)
{
    int b = blockIdx.x;
    int chunk = blockIdx.y;
    int c0 = chunk * 64;
    __shared__ unsigned int cnt[64 * 129];
    for (int i = threadIdx.x; i < 64 * 129; i += 256) cnt[i] = 0;
    __syncthreads();
    const int* nodes = idx + (long)b * 2 * E_;
    const int* edges = nodes + E_;
    for (int e = threadIdx.x; e < E_; e += 256) {
        int n = nodes[e];
        if ((n >> 6) == chunk) {
            int m = edges[e];
            atomicAdd(&cnt[(n & 63) * 129 + m], 1u);
        }
    }
    __syncthreads();
    for (int i = threadIdx.x; i < 64 * 128; i += 256) {
        int r = i >> 7, m = i & 127;
        Hmat[((long)(b * N_ + c0 + r)) * M_ + m] = f2bf((float)cnt[r * 129 + m]);
    }
    for (int i = threadIdx.x; i < 64 * 128; i += 256) {
        int m = i >> 6, r = i & 63;
        HmatT[((long)(b * M_ + m)) * N_ + c0 + r] = f2bf((float)cnt[r * 129 + m]);
    }
    if (threadIdx.x < 64) {
        int r = threadIdx.x;
        unsigned s = 0;
#pragma unroll 8
        for (int m = 0; m < 128; ++m) s += cnt[r * 129 + m];
        DinvN[b * N_ + c0 + r] = 1.0f / fmaxf((float)s, 1.0f);
    } else if (threadIdx.x < 192) {
        int m = threadIdx.x - 64;
        unsigned s = 0;
#pragma unroll 8
        for (int r = 0; r < 64; ++r) s += cnt[r * 129 + m];
        atomicAdd(&degM[b * M_ + m], (float)s);
    }
}

__global__ void inv_kernel(float* deg, int n) {
    int i = blockIdx.x * blockDim.x + threadIdx.x;
    if (i < n) deg[i] = 1.0f / fmaxf(deg[i], 1.0f);
}

// ---------- fp32 [R,C] -> SPLIT bf16 [C,R] batched transpose (thetas) -----
__global__ __launch_bounds__(256) void transpose_f32_bf16split(
    const float* __restrict__ in, long inStride,
    unsigned short* __restrict__ outT, long outStride, long loOff, int R, int C)
{
    int b = blockIdx.z;
    int r0 = blockIdx.y * 64, c0 = blockIdx.x * 64;
    __shared__ float tile[64][65];
    const float* ib = in + (long)b * inStride;
    unsigned short* ob = outT + (long)b * outStride;
    int x = threadIdx.x & 63;
    int y0 = threadIdx.x >> 6;
#pragma unroll
    for (int i = 0; i < 16; ++i) {
        int y = y0 * 16 + i;
        tile[y][x] = ib[(long)(r0 + y) * C + c0 + x];
    }
    __syncthreads();
#pragma unroll
    for (int i = 0; i < 16; ++i) {
        int y = y0 * 16 + i;
        float v = tile[x][y];
        unsigned short hv = f2bf(v);
        long idx = (long)(c0 + y) * R + r0 + x;
        ob[idx] = hv;
        ob[loOff + idx] = f2bf(v - bf2f(hv));
    }
}

// ======== fused layer: Z=Binv(H^T X) ; W=Theta^T Z^T ; hc^T=Dinv(W Hm^T)+b ;
//          BN over n ; ReLU ; write split actOut.  1 block = (batch, 64 h-rows)
__global__ __launch_bounds__(512, 2) void layer_kernel(
    const unsigned short* __restrict__ HmatT,   // [B][128][512]
    const unsigned short* __restrict__ Hmat,    // [B][512][128]
    const unsigned short* __restrict__ actIn, long actLo,
    const unsigned short* __restrict__ thT, long thLo,  // pre-offset to layer
    const float* __restrict__ BinvM, const float* __restrict__ DinvN,
    const float* __restrict__ convb, const float* __restrict__ gamma,
    const float* __restrict__ beta,
    unsigned short* __restrict__ actOut)
{
    __shared__ __align__(16) char lds[51200];
    unsigned short* As1  = (unsigned short*)lds;            // [128][40]
    unsigned short* Bs1h = As1 + 128 * 40;                  // [256][40]
    unsigned short* Bs1l = Bs1h + 256 * 40;                 // [256][40]
    unsigned short* Zch  = (unsigned short*)lds;            // [128][40]
    unsigned short* Zcl  = Zch + 128 * 40;
    unsigned short* As2h = Zcl + 128 * 40;                  // [64][40]
    unsigned short* As2l = As2h + 64 * 40;
    unsigned short* Wh   = (unsigned short*)lds;            // [64][136]
    unsigned short* Wl   = Wh + 64 * WTPAD;
    float* rsum = (float*)(lds + 64 * WTPAD * 2 * 2);       // [64][8]
    float* rsq  = rsum + 512;
    float2* prm = (float2*)(rsq + 512);                     // [64]

    int b = blockIdx.y, h0 = blockIdx.x * 64;
    int tid = threadIdx.x, wave = tid >> 6, lane = tid & 63;
    int lr = lane & 15, lq = lane >> 4;

    const unsigned short* HT  = HmatT + (long)b * M_ * N_;
    const unsigned short* Hm  = Hmat + (long)b * N_ * M_;
    const unsigned short* aIn = actIn + (long)b * H_ * N_;

    // ---------------- stage 1: Z[m][h'] = Binv[m] * sum_n HT[m][n]*act[h'][n]
    int wm1 = (wave >> 2) * 64;
    int wn1 = (wave & 3) * 64;
    floatx4 acc1[4][4] = {};
    for (int k0 = 0; k0 < N_; k0 += 32) {
        __syncthreads();
        {
            int r = tid >> 2, ck = (tid & 3) << 3;
            *(uint4*)&As1[r * 40 + ck] = *(const uint4*)&HT[(long)r * N_ + k0 + ck];
        }
#pragma unroll
        for (int i = tid; i < 1024; i += 512) {
            int r = i >> 2, ck = (i & 3) << 3;
            *(uint4*)&Bs1h[r * 40 + ck] = *(const uint4*)&aIn[(long)r * N_ + k0 + ck];
            *(uint4*)&Bs1l[r * 40 + ck] = *(const uint4*)&aIn[actLo + (long)r * N_ + k0 + ck];
        }
        __syncthreads();
        short8 af[4], bh[4], bl[4];
#pragma unroll
        for (int mt = 0; mt < 4; ++mt)
            af[mt] = *(const short8*)&As1[(wm1 + mt * 16 + lr) * 40 + lq * 8];
#pragma unroll
        for (int nt = 0; nt < 4; ++nt) {
            bh[nt] = *(const short8*)&Bs1h[(wn1 + nt * 16 + lr) * 40 + lq * 8];
            bl[nt] = *(const short8*)&Bs1l[(wn1 + nt * 16 + lr) * 40 + lq * 8];
        }
#pragma unroll
        for (int mt = 0; mt < 4; ++mt)
#pragma unroll
            for (int nt = 0; nt < 4; ++nt) {
                acc1[mt][nt] = __builtin_amdgcn_mfma_f32_16x16x32_bf16(
                    af[mt], bh[nt], acc1[mt][nt], 0, 0, 0);
                acc1[mt][nt] = __builtin_amdgcn_mfma_f32_16x16x32_bf16(
                    af[mt], bl[nt], acc1[mt][nt], 0, 0, 0);
            }
    }
    float rsB[4][4];
#pragma unroll
    for (int mt = 0; mt < 4; ++mt)
#pragma unroll
        for (int r4 = 0; r4 < 4; ++r4)
            rsB[mt][r4] = BinvM[b * M_ + wm1 + mt * 16 + lq * 4 + r4];

    // ---------------- stage 2: W[h][m] = sum_h' thT[h][h'] * Z[m][h']
    int wm2 = (wave >> 2) * 32, wn2 = (wave & 3) * 32;
    floatx4 acc2[2][2] = {};
    for (int k0 = 0; k0 < H_; k0 += 32) {
        __syncthreads();
        if ((wave & 3) == (k0 >> 6)) {
            int nt0 = (k0 >> 4) & 2;
#pragma unroll
            for (int ntl = 0; ntl < 4; ++ntl) {
                if ((ntl & 2) == nt0) {
                    int kk = ((ntl & 1) << 4) + lr;
#pragma unroll
                    for (int mtl = 0; mtl < 4; ++mtl)
#pragma unroll
                        for (int r4 = 0; r4 < 4; ++r4) {
                            int m = wm1 + mtl * 16 + lq * 4 + r4;
                            float v = acc1[mtl][ntl][r4] * rsB[mtl][r4];
                            unsigned short hv = f2bf(v);
                            Zch[m * 40 + kk] = hv;
                            Zcl[m * 40 + kk] = f2bf(v - bf2f(hv));
                        }
                }
            }
        }
        {
            int i = tid & 255, pl = tid >> 8;
            int r = i >> 2, ck = (i & 3) << 3;
            const unsigned short* src = thT + (pl ? thLo : 0) + (long)(h0 + r) * H_ + k0 + ck;
            *(uint4*)((pl ? As2l : As2h) + r * 40 + ck) = *(const uint4*)src;
        }
        __syncthreads();
        short8 ah[2], al[2], zb[2], zl[2];
#pragma unroll
        for (int mt = 0; mt < 2; ++mt) {
            ah[mt] = *(const short8*)&As2h[(wm2 + mt * 16 + lr) * 40 + lq * 8];
            al[mt] = *(const short8*)&As2l[(wm2 + mt * 16 + lr) * 40 + lq * 8];
        }
#pragma unroll
        for (int nt = 0; nt < 2; ++nt) {
            zb[nt] = *(const short8*)&Zch[(wn2 + nt * 16 + lr) * 40 + lq * 8];
            zl[nt] = *(const short8*)&Zcl[(wn2 + nt * 16 + lr) * 40 + lq * 8];
        }
#pragma unroll
        for (int mt = 0; mt < 2; ++mt)
#pragma unroll
            for (int nt = 0; nt < 2; ++nt) {
                acc2[mt][nt] = __builtin_amdgcn_mfma_f32_16x16x32_bf16(
                    ah[mt], zb[nt], acc2[mt][nt], 0, 0, 0);
                acc2[mt][nt] = __builtin_amdgcn_mfma_f32_16x16x32_bf16(
                    ah[mt], zl[nt], acc2[mt][nt], 0, 0, 0);
                acc2[mt][nt] = __builtin_amdgcn_mfma_f32_16x16x32_bf16(
                    al[mt], zb[nt], acc2[mt][nt], 0, 0, 0);
            }
    }
    __syncthreads();
#pragma unroll
    for (int mt = 0; mt < 2; ++mt)
#pragma unroll
        for (int r4 = 0; r4 < 4; ++r4) {
            int row = wm2 + mt * 16 + lq * 4 + r4;
#pragma unroll
            for (int nt = 0; nt < 2; ++nt) {
                int col = wn2 + nt * 16 + lr;
                float v = acc2[mt][nt][r4];
                unsigned short hv = f2bf(v);
                Wh[row * WTPAD + col] = hv;
                Wl[row * WTPAD + col] = f2bf(v - bf2f(hv));
            }
        }
    __syncthreads();

    // ---------------- stage 3: hc^T[h][n] = Dinv[n]*sum_m W[h][m]*Hm[n][m]+cb
    int wn3 = wave * 64;
    floatx4 acc3[4][4] = {};
    for (int k0 = 0; k0 < M_; k0 += 32) {
        short8 ah[4], al[4], bh3[4];
#pragma unroll
        for (int nt = 0; nt < 4; ++nt)
            bh3[nt] = *(const short8*)&Hm[(long)(wn3 + nt * 16 + lr) * M_ + k0 + lq * 8];
#pragma unroll
        for (int mt = 0; mt < 4; ++mt) {
            ah[mt] = *(const short8*)&Wh[(mt * 16 + lr) * WTPAD + k0 + lq * 8];
            al[mt] = *(const short8*)&Wl[(mt * 16 + lr) * WTPAD + k0 + lq * 8];
        }
#pragma unroll
        for (int mt = 0; mt < 4; ++mt)
#pragma unroll
            for (int nt = 0; nt < 4; ++nt) {
                acc3[mt][nt] = __builtin_amdgcn_mfma_f32_16x16x32_bf16(
                    ah[mt], bh3[nt], acc3[mt][nt], 0, 0, 0);
                acc3[mt][nt] = __builtin_amdgcn_mfma_f32_16x16x32_bf16(
                    al[mt], bh3[nt], acc3[mt][nt], 0, 0, 0);
            }
    }

    float dv[4];
#pragma unroll
    for (int nt = 0; nt < 4; ++nt)
        dv[nt] = DinvN[b * N_ + wn3 + nt * 16 + lr];
    float cb[4][4];
#pragma unroll
    for (int mt = 0; mt < 4; ++mt)
#pragma unroll
        for (int r4 = 0; r4 < 4; ++r4)
            cb[mt][r4] = convb[h0 + mt * 16 + lq * 4 + r4];
#pragma unroll
    for (int mt = 0; mt < 4; ++mt)
#pragma unroll
        for (int nt = 0; nt < 4; ++nt)
#pragma unroll
            for (int r4 = 0; r4 < 4; ++r4)
                acc3[mt][nt][r4] = acc3[mt][nt][r4] * dv[nt] + cb[mt][r4];

    float ps[4][4], pq[4][4];
#pragma unroll
    for (int mt = 0; mt < 4; ++mt)
#pragma unroll
        for (int r4 = 0; r4 < 4; ++r4) {
            float s = 0.f, q = 0.f;
#pragma unroll
            for (int nt = 0; nt < 4; ++nt) {
                float v = acc3[mt][nt][r4];
                s += v; q += v * v;
            }
            ps[mt][r4] = s; pq[mt][r4] = q;
        }
#pragma unroll
    for (int mask = 1; mask <= 8; mask <<= 1) {
#pragma unroll
        for (int mt = 0; mt < 4; ++mt)
#pragma unroll
            for (int r4 = 0; r4 < 4; ++r4) {
                ps[mt][r4] += __shfl_xor(ps[mt][r4], mask);
                pq[mt][r4] += __shfl_xor(pq[mt][r4], mask);
            }
    }
    if (lr == 0) {
#pragma unroll
        for (int mt = 0; mt < 4; ++mt)
#pragma unroll
            for (int r4 = 0; r4 < 4; ++r4) {
                int row = mt * 16 + lq * 4 + r4;
                rsum[row * 8 + wave] = ps[mt][r4];
                rsq[row * 8 + wave]  = pq[mt][r4];
            }
    }
    __syncthreads();
    if (tid < 64) {
        float s = 0.f, s2 = 0.f;
#pragma unroll
        for (int w = 0; w < 8; ++w) { s += rsum[tid * 8 + w]; s2 += rsq[tid * 8 + w]; }
        float mu  = s * (1.0f / N_);
        float var = fmaxf(s2 * (1.0f / N_) - mu * mu, 0.f);
        float sc  = gamma[h0 + tid] * rsqrtf(var + EPS_);
        prm[tid] = make_float2(sc, beta[h0 + tid] - mu * sc);
    }
    __syncthreads();

    unsigned short* ab = actOut + (long)b * H_ * N_;
#pragma unroll
    for (int mt = 0; mt < 4; ++mt)
#pragma unroll
        for (int r4 = 0; r4 < 4; ++r4) {
            int row = mt * 16 + lq * 4 + r4;
            float2 p = prm[row];
#pragma unroll
            for (int nt = 0; nt < 4; ++nt) {
                float y = fmaxf(acc3[mt][nt][r4] * p.x + p.y, 0.f);
                unsigned short hv = f2bf(y);
                long idx = (long)(h0 + row) * N_ + wn3 + nt * 16 + lr;
                ab[idx] = hv;
                ab[actLo + idx] = f2bf(y - bf2f(hv));
            }
        }
}

// ---- comb[n][h] = hT[h][n] + actT[h][n] (hi+lo), fp32 --------------------
__global__ __launch_bounds__(256) void comb_transpose_kernel(
    const unsigned short* __restrict__ actT, long actLo,
    const float* __restrict__ hT, float* __restrict__ comb)
{
    int b  = blockIdx.z;
    int n0 = blockIdx.x * 64, h0 = blockIdx.y * 64;
    __shared__ float tile[64][65];
    const unsigned short* ab = actT + (long)b * H_ * N_;
    const float* hb = hT + (long)b * H_ * N_;
    int x = threadIdx.x & 63, y0 = threadIdx.x >> 6;
#pragma unroll
    for (int i = 0; i < 16; ++i) {
        int y = y0 * 16 + i;
        long idx = (long)(h0 + y) * N_ + n0 + x;
        tile[y][x] = bf2f(ab[idx]) + bf2f(ab[actLo + idx]) + hb[idx];
    }
    __syncthreads();
#pragma unroll
    for (int i = 0; i < 16; ++i) {
        int y = y0 * 16 + i;
        comb[((long)b * N_ + n0 + y) * H_ + h0 + x] = tile[x][y];
    }
}

// -------------------- fp32 tiled GEMM (decoder only) ----------------------
__global__ __launch_bounds__(256) void gemm_kernel(
    const float* __restrict__ A, long aStride,
    const float* __restrict__ Bm, long bStride,
    float* __restrict__ C, long cStride,
    int M, int Nn, int K,
    const float* __restrict__ bias)
{
    int b  = blockIdx.z;
    int m0 = blockIdx.y * TILE;
    int n0 = blockIdx.x * TILE;
    const float* Ab = A + (long)b * aStride;
    const float* Bb = Bm + (long)b * bStride;
    float*       Cb = C + (long)b * cStride;

    __shared__ float As[KC][TILE];
    __shared__ float Bs[KC][TILE];

    int tid = threadIdx.x;
    int tx4 = (tid & 15) << 2;
    int ty4 = (tid >> 4) << 2;
    int lr  = tid >> 2;
    int lc4 = (tid & 3) << 2;
    int br  = tid >> 4;
    int bc4 = (tid & 15) << 2;

    float acc[4][4] = {};

    for (int k0 = 0; k0 < K; k0 += KC) {
        float4 av = *(const float4*)(Ab + (long)(m0 + lr) * K + k0 + lc4);
        As[lc4 + 0][lr] = av.x;
        As[lc4 + 1][lr] = av.y;
        As[lc4 + 2][lr] = av.z;
        As[lc4 + 3][lr] = av.w;
        int cc = n0 + bc4;
        float4 bv = make_float4(0.f, 0.f, 0.f, 0.f);
        const float* bp = Bb + (long)(k0 + br) * Nn + cc;
        if (cc + 3 < Nn) {
            bv = *(const float4*)bp;
        } else {
            if (cc + 0 < Nn) bv.x = bp[0];
            if (cc + 1 < Nn) bv.y = bp[1];
            if (cc + 2 < Nn) bv.z = bp[2];
            if (cc + 3 < Nn) bv.w = bp[3];
        }
        *(float4*)&Bs[br][bc4] = bv;
        __syncthreads();
#pragma unroll
        for (int kk = 0; kk < KC; ++kk) {
            float4 a  = *(const float4*)&As[kk][ty4];
            float4 bq = *(const float4*)&Bs[kk][tx4];
            acc[0][0] += a.x * bq.x; acc[0][1] += a.x * bq.y;
            acc[0][2] += a.x * bq.z; acc[0][3] += a.x * bq.w;
            acc[1][0] += a.y * bq.x; acc[1][1] += a.y * bq.y;
            acc[1][2] += a.y * bq.z; acc[1][3] += a.y * bq.w;
            acc[2][0] += a.z * bq.x; acc[2][1] += a.z * bq.y;
            acc[2][2] += a.z * bq.z; acc[2][3] += a.z * bq.w;
            acc[3][0] += a.w * bq.x; acc[3][1] += a.w * bq.y;
            acc[3][2] += a.w * bq.z; acc[3][3] += a.w * bq.w;
        }
        __syncthreads();
    }

#pragma unroll
    for (int i = 0; i < 4; ++i) {
        int r = m0 + ty4 + i;
#pragma unroll
        for (int j = 0; j < 4; ++j) {
            int c = n0 + tx4 + j;
            if (c < Nn)
                Cb[(long)r * Nn + c] = acc[i][j] + (bias ? bias[c] : 0.f);
        }
    }
}

// --------------------------------------------------------------------------
extern "C" void kernel_launch(void* const* d_in, const int* in_sizes, int n_in,
                              void* d_out, int out_size, void* d_ws, size_t ws_size,
                              hipStream_t stream) {
    const float* obs    = (const float*)d_in[0];
    const int*   hyper  = (const int*)d_in[1];
    const float* Wenc   = (const float*)d_in[2];
    const float* benc   = (const float*)d_in[3];
    const float* thetas = (const float*)d_in[4];
    const float* convb  = (const float*)d_in[5];
    const float* gammas = (const float*)d_in[6];
    const float* betas  = (const float*)d_in[7];
    const float* Wdec   = (const float*)d_in[8];
    const float* bdec   = (const float*)d_in[9];
    float* out = (float*)d_out;

    char* w = (char*)d_ws;
    auto alloc = [&](size_t bytes) { char* p = w; w += (bytes + 255) & ~255ULL; return p; };
    float* hT    = (float*)alloc((size_t)B_ * H_ * N_ * 4);
    float* comb  = (float*)alloc((size_t)B_ * N_ * H_ * 4);
    float* DinvN = (float*)alloc((size_t)B_ * N_ * 4);
    float* BinvM = (float*)alloc((size_t)B_ * M_ * 4);
    unsigned short* Hmat  = (unsigned short*)alloc((size_t)B_ * N_ * M_ * 2);
    unsigned short* HmatT = (unsigned short*)alloc((size_t)B_ * M_ * N_ * 2);
    unsigned short* actA  = (unsigned short*)alloc((size_t)B_ * H_ * N_ * 2 * 2);
    unsigned short* actB  = (unsigned short*)alloc((size_t)B_ * H_ * N_ * 2 * 2);
    unsigned short* thT   = (unsigned short*)alloc((size_t)L_ * H_ * H_ * 2 * 2);

    const long actLo = (long)B_ * H_ * N_;
    const long thLo  = (long)L_ * H_ * H_;

    hipMemsetAsync(BinvM, 0, (size_t)B_ * M_ * 4, stream);
    encoder3_kernel<<<dim3(B_, 4), 512, 0, stream>>>(obs, Wenc, benc, hT, actA, actLo);
    build_kernel<<<dim3(B_, 8), 256, 0, stream>>>(hyper, Hmat, HmatT, DinvN, BinvM);
    inv_kernel<<<(B_ * M_ + 255) / 256, 256, 0, stream>>>(BinvM, B_ * M_);
    transpose_f32_bf16split<<<dim3(4, 4, 3), 256, 0, stream>>>(
        thetas, (long)H_ * H_, thT, (long)H_ * H_, thLo, H_, H_);

    const unsigned short* cur = actA;
    unsigned short* nxt = actB;
    for (int l = 0; l < L_; ++l) {
        layer_kernel<<<dim3(4, B_), 512, 0, stream>>>(
            HmatT, Hmat, cur, actLo, thT + (size_t)l * H_ * H_, thLo,
            BinvM, DinvN, convb + (size_t)l * H_,
            gammas + (size_t)l * H_, betas + (size_t)l * H_, nxt);
        const unsigned short* t = cur; cur = nxt; nxt = (unsigned short*)t;
    }
    // comb = h + h_social  (cur holds final activations)
    comb_transpose_kernel<<<dim3(8, 4, B_), 256, 0, stream>>>(cur, actLo, hT, comb);
    // out = comb @ Wdec + bdec (fp32)
    gemm_kernel<<<dim3(1, N_ / TILE, B_), 256, 0, stream>>>(
        comb, (long)N_ * H_, Wdec, 0,
        out, (long)N_ * P2_, N_, P2_, H_, bdec);
}

// Round 8
// 284.130 us; speedup vs baseline: 1.5991x; 1.1808x over previous
//
#include <hip/hip_runtime.h>
#include <hip/hip_bf16.h>

#define B_   64
#define N_   512
#define T_   8
#define DIN_ 2
#define H_   256
#define L_   3
#define E_   8192
#define M_   128
#define P2_  24   // P*2
#define EPS_ 1e-5f

#define TILE 64
#define KC   16
#define WTPAD 136

typedef __attribute__((ext_vector_type(8))) short short8;
typedef __attribute__((ext_vector_type(4))) float floatx4;

__device__ __forceinline__ unsigned short f2bf(float f) {
    union { float f; unsigned u; } v; v.f = f;
    unsigned r = v.u + 0x7FFF + ((v.u >> 16) & 1);
    return (unsigned short)(r >> 16);
}
__device__ __forceinline__ float bf2f(unsigned short h) {
    union { unsigned u; float f; } v; v.u = (unsigned)h << 16; return v.f;
}

// ---- encoder: hT[b,c,n] fp32 + actT[b,c,n] split bf16 (mean_t relu) ------
__global__ __launch_bounds__(512, 4) void encoder3_kernel(
    const float* __restrict__ obs, const float* __restrict__ Wenc,
    const float* __restrict__ benc, float* __restrict__ hT,
    unsigned short* __restrict__ actT, long actLo)
{
    int b = blockIdx.x, h0 = blockIdx.y * 64;
    __shared__ float ot[16 * 513];
    const float4* src = (const float4*)(obs + (long)b * N_ * 16);
    int tid = threadIdx.x;
    for (int i = tid; i < 2048; i += 512) {
        float4 v = src[i];
        int n = i >> 2, k4 = (i & 3) << 2;
        ot[(k4 + 0) * 513 + n] = v.x;
        ot[(k4 + 1) * 513 + n] = v.y;
        ot[(k4 + 2) * 513 + n] = v.z;
        ot[(k4 + 3) * 513 + n] = v.w;
    }
    __syncthreads();
    int wave = tid >> 6, lane = tid & 63;
    int cbase = h0 + wave * 8;
    float w0[8], w1[8], bb[8];
#pragma unroll
    for (int i = 0; i < 8; ++i) {
        w0[i] = Wenc[cbase + i];
        w1[i] = Wenc[H_ + cbase + i];
        bb[i] = benc[cbase + i];
    }
    for (int j = 0; j < 8; ++j) {
        int n = j * 64 + lane;
        float x0[8], x1[8];
#pragma unroll
        for (int t = 0; t < 8; ++t) {
            x0[t] = ot[(2 * t) * 513 + n];
            x1[t] = ot[(2 * t + 1) * 513 + n];
        }
#pragma unroll
        for (int i = 0; i < 8; ++i) {
            float acc = 0.f;
#pragma unroll
            for (int t = 0; t < 8; ++t)
                acc += fmaxf(x0[t] * w0[i] + x1[t] * w1[i] + bb[i], 0.f);
            acc *= 0.125f;
            long idx = ((long)b * H_ + cbase + i) * N_ + n;
            hT[idx] = acc;
            unsigned short hv = f2bf(acc);
            actT[idx] = hv;
            actT[actLo + idx] = f2bf(acc - bf2f(hv));
        }
    }
}

// -------------------- densify incidence via LDS counts --------------------
__global__ __launch_bounds__(256) void build_kernel(const int* __restrict__ idx,
    unsigned short* __restrict__ Hmat, unsigned short* __restrict__ HmatT,
    float* __restrict__ DinvN, float* __restrict__ degM)
{
    int b = blockIdx.x;
    int chunk = blockIdx.y;
    int c0 = chunk * 64;
    __shared__ unsigned int cnt[64 * 129];
    for (int i = threadIdx.x; i < 64 * 129; i += 256) cnt[i] = 0;
    __syncthreads();
    const int* nodes = idx + (long)b * 2 * E_;
    const int* edges = nodes + E_;
    for (int e = threadIdx.x; e < E_; e += 256) {
        int n = nodes[e];
        if ((n >> 6) == chunk) {
            int m = edges[e];
            atomicAdd(&cnt[(n & 63) * 129 + m], 1u);
        }
    }
    __syncthreads();
    for (int i = threadIdx.x; i < 64 * 128; i += 256) {
        int r = i >> 7, m = i & 127;
        Hmat[((long)(b * N_ + c0 + r)) * M_ + m] = f2bf((float)cnt[r * 129 + m]);
    }
    for (int i = threadIdx.x; i < 64 * 128; i += 256) {
        int m = i >> 6, r = i & 63;
        HmatT[((long)(b * M_ + m)) * N_ + c0 + r] = f2bf((float)cnt[r * 129 + m]);
    }
    if (threadIdx.x < 64) {
        int r = threadIdx.x;
        unsigned s = 0;
#pragma unroll 8
        for (int m = 0; m < 128; ++m) s += cnt[r * 129 + m];
        DinvN[b * N_ + c0 + r] = 1.0f / fmaxf((float)s, 1.0f);
    } else if (threadIdx.x < 192) {
        int m = threadIdx.x - 64;
        unsigned s = 0;
#pragma unroll 8
        for (int r = 0; r < 64; ++r) s += cnt[r * 129 + m];
        atomicAdd(&degM[b * M_ + m], (float)s);
    }
}

__global__ void inv_kernel(float* deg, int n) {
    int i = blockIdx.x * blockDim.x + threadIdx.x;
    if (i < n) deg[i] = 1.0f / fmaxf(deg[i], 1.0f);
}

// ---------- fp32 [R,C] -> SPLIT bf16 [C,R] batched transpose (thetas) -----
__global__ __launch_bounds__(256) void transpose_f32_bf16split(
    const float* __restrict__ in, long inStride,
    unsigned short* __restrict__ outT, long outStride, long loOff, int R, int C)
{
    int b = blockIdx.z;
    int r0 = blockIdx.y * 64, c0 = blockIdx.x * 64;
    __shared__ float tile[64][65];
    const float* ib = in + (long)b * inStride;
    unsigned short* ob = outT + (long)b * outStride;
    int x = threadIdx.x & 63;
    int y0 = threadIdx.x >> 6;
#pragma unroll
    for (int i = 0; i < 16; ++i) {
        int y = y0 * 16 + i;
        tile[y][x] = ib[(long)(r0 + y) * C + c0 + x];
    }
    __syncthreads();
#pragma unroll
    for (int i = 0; i < 16; ++i) {
        int y = y0 * 16 + i;
        float v = tile[x][y];
        unsigned short hv = f2bf(v);
        long idx = (long)(c0 + y) * R + r0 + x;
        ob[idx] = hv;
        ob[loOff + idx] = f2bf(v - bf2f(hv));
    }
}

// ======== fused layer: Z=Binv(H^T X) ; W=Theta^T Z^T ; hc^T=Dinv(W Hm^T)+b ;
//          BN over n ; ReLU ; write split actOut.  1 block = (batch, 64 h-rows)
// XCD swizzle: a batch's 4 chunks get linear ids spaced by 8 -> same XCD ->
// shared L2 window for actIn/HmatT/Hmat re-reads. Register prefetch pipelines
// the k+1 staging loads behind MFMA.
__global__ __launch_bounds__(512, 2) void layer_kernel(
    const unsigned short* __restrict__ HmatT,   // [B][128][512]
    const unsigned short* __restrict__ Hmat,    // [B][512][128]
    const unsigned short* __restrict__ actIn, long actLo,
    const unsigned short* __restrict__ thT, long thLo,  // pre-offset to layer
    const float* __restrict__ BinvM, const float* __restrict__ DinvN,
    const float* __restrict__ convb, const float* __restrict__ gamma,
    const float* __restrict__ beta,
    unsigned short* __restrict__ actOut)
{
    __shared__ __align__(16) char lds[51200];
    unsigned short* As1  = (unsigned short*)lds;            // [128][40]
    unsigned short* Bs1h = As1 + 128 * 40;                  // [256][40]
    unsigned short* Bs1l = Bs1h + 256 * 40;                 // [256][40]
    unsigned short* Zch  = (unsigned short*)lds;            // [128][40]
    unsigned short* Zcl  = Zch + 128 * 40;
    unsigned short* As2h = Zcl + 128 * 40;                  // [64][40]
    unsigned short* As2l = As2h + 64 * 40;
    unsigned short* Wh   = (unsigned short*)lds;            // [64][136]
    unsigned short* Wl   = Wh + 64 * WTPAD;
    float* rsum = (float*)(lds + 64 * WTPAD * 2 * 2);       // [64][8]
    float* rsq  = rsum + 512;
    float2* prm = (float2*)(rsq + 512);                     // [64]

    // XCD-aware swizzle (perf heuristic only)
    int id = blockIdx.x + (blockIdx.y << 2);
    int xcd = id & 7, slot = id >> 3;
    int b  = ((slot >> 2) << 3) + xcd;
    int h0 = (slot & 3) * 64;

    int tid = threadIdx.x, wave = tid >> 6, lane = tid & 63;
    int lr = lane & 15, lq = lane >> 4;

    const unsigned short* HT  = HmatT + (long)b * M_ * N_;
    const unsigned short* Hm  = Hmat + (long)b * N_ * M_;
    const unsigned short* aIn = actIn + (long)b * H_ * N_;

    // ---------------- stage 1: Z[m][h'] = Binv[m] * sum_n HT[m][n]*act[h'][n]
    int wm1 = (wave >> 2) * 64;
    int wn1 = (wave & 3) * 64;
    floatx4 acc1[4][4] = {};
    // loader indices
    int r1 = tid >> 2, ck1 = (tid & 3) << 3;        // As1: 1 uint4/thread
    int rB0 = tid >> 2, rB1 = (tid + 512) >> 2;     // Bs: 2 rows/thread
    // prologue prefetch (k0 = 0)
    uint4 pA  = *(const uint4*)&HT[(long)r1 * N_ + ck1];
    uint4 pBh0 = *(const uint4*)&aIn[(long)rB0 * N_ + ck1];
    uint4 pBl0 = *(const uint4*)&aIn[actLo + (long)rB0 * N_ + ck1];
    uint4 pBh1 = *(const uint4*)&aIn[(long)rB1 * N_ + ck1];
    uint4 pBl1 = *(const uint4*)&aIn[actLo + (long)rB1 * N_ + ck1];
    for (int k0 = 0; k0 < N_; k0 += 32) {
        __syncthreads();
        *(uint4*)&As1[r1 * 40 + ck1]  = pA;
        *(uint4*)&Bs1h[rB0 * 40 + ck1] = pBh0;
        *(uint4*)&Bs1l[rB0 * 40 + ck1] = pBl0;
        *(uint4*)&Bs1h[rB1 * 40 + ck1] = pBh1;
        *(uint4*)&Bs1l[rB1 * 40 + ck1] = pBl1;
        __syncthreads();
        int kn = k0 + 32;
        if (kn < N_) {   // prefetch next tile; flies behind ds_read+MFMA
            pA   = *(const uint4*)&HT[(long)r1 * N_ + kn + ck1];
            pBh0 = *(const uint4*)&aIn[(long)rB0 * N_ + kn + ck1];
            pBl0 = *(const uint4*)&aIn[actLo + (long)rB0 * N_ + kn + ck1];
            pBh1 = *(const uint4*)&aIn[(long)rB1 * N_ + kn + ck1];
            pBl1 = *(const uint4*)&aIn[actLo + (long)rB1 * N_ + kn + ck1];
        }
        short8 af[4], bh[4], bl[4];
#pragma unroll
        for (int mt = 0; mt < 4; ++mt)
            af[mt] = *(const short8*)&As1[(wm1 + mt * 16 + lr) * 40 + lq * 8];
#pragma unroll
        for (int nt = 0; nt < 4; ++nt) {
            bh[nt] = *(const short8*)&Bs1h[(wn1 + nt * 16 + lr) * 40 + lq * 8];
            bl[nt] = *(const short8*)&Bs1l[(wn1 + nt * 16 + lr) * 40 + lq * 8];
        }
#pragma unroll
        for (int mt = 0; mt < 4; ++mt)
#pragma unroll
            for (int nt = 0; nt < 4; ++nt) {
                acc1[mt][nt] = __builtin_amdgcn_mfma_f32_16x16x32_bf16(
                    af[mt], bh[nt], acc1[mt][nt], 0, 0, 0);
                acc1[mt][nt] = __builtin_amdgcn_mfma_f32_16x16x32_bf16(
                    af[mt], bl[nt], acc1[mt][nt], 0, 0, 0);
            }
    }
    float rsB[4][4];
#pragma unroll
    for (int mt = 0; mt < 4; ++mt)
#pragma unroll
        for (int r4 = 0; r4 < 4; ++r4)
            rsB[mt][r4] = BinvM[b * M_ + wm1 + mt * 16 + lq * 4 + r4];

    // ---------------- stage 2: W[h][m] = sum_h' thT[h][h'] * Z[m][h']
    int wm2 = (wave >> 2) * 32, wn2 = (wave & 3) * 32;
    int i2 = tid & 255, pl2 = tid >> 8;
    int r2 = i2 >> 2, ck2 = (i2 & 3) << 3;
    const unsigned short* thBase = thT + (pl2 ? thLo : 0) + (long)(h0 + r2) * H_ + ck2;
    unsigned short* As2dst = (pl2 ? As2l : As2h) + r2 * 40 + ck2;
    uint4 pTh = *(const uint4*)thBase;
    floatx4 acc2[2][2] = {};
    for (int k0 = 0; k0 < H_; k0 += 32) {
        __syncthreads();
        if ((wave & 3) == (k0 >> 6)) {
            int nt0 = (k0 >> 4) & 2;
#pragma unroll
            for (int ntl = 0; ntl < 4; ++ntl) {
                if ((ntl & 2) == nt0) {
                    int kk = ((ntl & 1) << 4) + lr;
#pragma unroll
                    for (int mtl = 0; mtl < 4; ++mtl)
#pragma unroll
                        for (int r4 = 0; r4 < 4; ++r4) {
                            int m = wm1 + mtl * 16 + lq * 4 + r4;
                            float v = acc1[mtl][ntl][r4] * rsB[mtl][r4];
                            unsigned short hv = f2bf(v);
                            Zch[m * 40 + kk] = hv;
                            Zcl[m * 40 + kk] = f2bf(v - bf2f(hv));
                        }
                }
            }
        }
        *(uint4*)As2dst = pTh;
        __syncthreads();
        if (k0 + 32 < H_) pTh = *(const uint4*)(thBase + k0 + 32);
        short8 ah[2], al[2], zb[2], zl[2];
#pragma unroll
        for (int mt = 0; mt < 2; ++mt) {
            ah[mt] = *(const short8*)&As2h[(wm2 + mt * 16 + lr) * 40 + lq * 8];
            al[mt] = *(const short8*)&As2l[(wm2 + mt * 16 + lr) * 40 + lq * 8];
        }
#pragma unroll
        for (int nt = 0; nt < 2; ++nt) {
            zb[nt] = *(const short8*)&Zch[(wn2 + nt * 16 + lr) * 40 + lq * 8];
            zl[nt] = *(const short8*)&Zcl[(wn2 + nt * 16 + lr) * 40 + lq * 8];
        }
#pragma unroll
        for (int mt = 0; mt < 2; ++mt)
#pragma unroll
            for (int nt = 0; nt < 2; ++nt) {
                acc2[mt][nt] = __builtin_amdgcn_mfma_f32_16x16x32_bf16(
                    ah[mt], zb[nt], acc2[mt][nt], 0, 0, 0);
                acc2[mt][nt] = __builtin_amdgcn_mfma_f32_16x16x32_bf16(
                    ah[mt], zl[nt], acc2[mt][nt], 0, 0, 0);
                acc2[mt][nt] = __builtin_amdgcn_mfma_f32_16x16x32_bf16(
                    al[mt], zb[nt], acc2[mt][nt], 0, 0, 0);
            }
    }
    __syncthreads();
#pragma unroll
    for (int mt = 0; mt < 2; ++mt)
#pragma unroll
        for (int r4 = 0; r4 < 4; ++r4) {
            int row = wm2 + mt * 16 + lq * 4 + r4;
#pragma unroll
            for (int nt = 0; nt < 2; ++nt) {
                int col = wn2 + nt * 16 + lr;
                float v = acc2[mt][nt][r4];
                unsigned short hv = f2bf(v);
                Wh[row * WTPAD + col] = hv;
                Wl[row * WTPAD + col] = f2bf(v - bf2f(hv));
            }
        }
    __syncthreads();

    // ---------------- stage 3: hc^T[h][n] = Dinv[n]*sum_m W[h][m]*Hm[n][m]+cb
    int wn3 = wave * 64;
    floatx4 acc3[4][4] = {};
    for (int k0 = 0; k0 < M_; k0 += 32) {
        short8 ah[4], al[4], bh3[4];
#pragma unroll
        for (int nt = 0; nt < 4; ++nt)
            bh3[nt] = *(const short8*)&Hm[(long)(wn3 + nt * 16 + lr) * M_ + k0 + lq * 8];
#pragma unroll
        for (int mt = 0; mt < 4; ++mt) {
            ah[mt] = *(const short8*)&Wh[(mt * 16 + lr) * WTPAD + k0 + lq * 8];
            al[mt] = *(const short8*)&Wl[(mt * 16 + lr) * WTPAD + k0 + lq * 8];
        }
#pragma unroll
        for (int mt = 0; mt < 4; ++mt)
#pragma unroll
            for (int nt = 0; nt < 4; ++nt) {
                acc3[mt][nt] = __builtin_amdgcn_mfma_f32_16x16x32_bf16(
                    ah[mt], bh3[nt], acc3[mt][nt], 0, 0, 0);
                acc3[mt][nt] = __builtin_amdgcn_mfma_f32_16x16x32_bf16(
                    al[mt], bh3[nt], acc3[mt][nt], 0, 0, 0);
            }
    }

    float dv[4];
#pragma unroll
    for (int nt = 0; nt < 4; ++nt)
        dv[nt] = DinvN[b * N_ + wn3 + nt * 16 + lr];
    float cb[4][4];
#pragma unroll
    for (int mt = 0; mt < 4; ++mt)
#pragma unroll
        for (int r4 = 0; r4 < 4; ++r4)
            cb[mt][r4] = convb[h0 + mt * 16 + lq * 4 + r4];
#pragma unroll
    for (int mt = 0; mt < 4; ++mt)
#pragma unroll
        for (int nt = 0; nt < 4; ++nt)
#pragma unroll
            for (int r4 = 0; r4 < 4; ++r4)
                acc3[mt][nt][r4] = acc3[mt][nt][r4] * dv[nt] + cb[mt][r4];

    float ps[4][4], pq[4][4];
#pragma unroll
    for (int mt = 0; mt < 4; ++mt)
#pragma unroll
        for (int r4 = 0; r4 < 4; ++r4) {
            float s = 0.f, q = 0.f;
#pragma unroll
            for (int nt = 0; nt < 4; ++nt) {
                float v = acc3[mt][nt][r4];
                s += v; q += v * v;
            }
            ps[mt][r4] = s; pq[mt][r4] = q;
        }
#pragma unroll
    for (int mask = 1; mask <= 8; mask <<= 1) {
#pragma unroll
        for (int mt = 0; mt < 4; ++mt)
#pragma unroll
            for (int r4 = 0; r4 < 4; ++r4) {
                ps[mt][r4] += __shfl_xor(ps[mt][r4], mask);
                pq[mt][r4] += __shfl_xor(pq[mt][r4], mask);
            }
    }
    if (lr == 0) {
#pragma unroll
        for (int mt = 0; mt < 4; ++mt)
#pragma unroll
            for (int r4 = 0; r4 < 4; ++r4) {
                int row = mt * 16 + lq * 4 + r4;
                rsum[row * 8 + wave] = ps[mt][r4];
                rsq[row * 8 + wave]  = pq[mt][r4];
            }
    }
    __syncthreads();
    if (tid < 64) {
        float s = 0.f, s2 = 0.f;
#pragma unroll
        for (int w = 0; w < 8; ++w) { s += rsum[tid * 8 + w]; s2 += rsq[tid * 8 + w]; }
        float mu  = s * (1.0f / N_);
        float var = fmaxf(s2 * (1.0f / N_) - mu * mu, 0.f);
        float sc  = gamma[h0 + tid] * rsqrtf(var + EPS_);
        prm[tid] = make_float2(sc, beta[h0 + tid] - mu * sc);
    }
    __syncthreads();

    unsigned short* ab = actOut + (long)b * H_ * N_;
#pragma unroll
    for (int mt = 0; mt < 4; ++mt)
#pragma unroll
        for (int r4 = 0; r4 < 4; ++r4) {
            int row = mt * 16 + lq * 4 + r4;
            float2 p = prm[row];
#pragma unroll
            for (int nt = 0; nt < 4; ++nt) {
                float y = fmaxf(acc3[mt][nt][r4] * p.x + p.y, 0.f);
                unsigned short hv = f2bf(y);
                long idx = (long)(h0 + row) * N_ + wn3 + nt * 16 + lr;
                ab[idx] = hv;
                ab[actLo + idx] = f2bf(y - bf2f(hv));
            }
        }
}

// ---- comb[n][h] = hT[h][n] + actT[h][n] (hi+lo), fp32 --------------------
__global__ __launch_bounds__(256) void comb_transpose_kernel(
    const unsigned short* __restrict__ actT, long actLo,
    const float* __restrict__ hT, float* __restrict__ comb)
{
    int b  = blockIdx.z;
    int n0 = blockIdx.x * 64, h0 = blockIdx.y * 64;
    __shared__ float tile[64][65];
    const unsigned short* ab = actT + (long)b * H_ * N_;
    const float* hb = hT + (long)b * H_ * N_;
    int x = threadIdx.x & 63, y0 = threadIdx.x >> 6;
#pragma unroll
    for (int i = 0; i < 16; ++i) {
        int y = y0 * 16 + i;
        long idx = (long)(h0 + y) * N_ + n0 + x;
        tile[y][x] = bf2f(ab[idx]) + bf2f(ab[actLo + idx]) + hb[idx];
    }
    __syncthreads();
#pragma unroll
    for (int i = 0; i < 16; ++i) {
        int y = y0 * 16 + i;
        comb[((long)b * N_ + n0 + y) * H_ + h0 + x] = tile[x][y];
    }
}

// -------------------- fp32 tiled GEMM (decoder only) ----------------------
__global__ __launch_bounds__(256) void gemm_kernel(
    const float* __restrict__ A, long aStride,
    const float* __restrict__ Bm, long bStride,
    float* __restrict__ C, long cStride,
    int M, int Nn, int K,
    const float* __restrict__ bias)
{
    int b  = blockIdx.z;
    int m0 = blockIdx.y * TILE;
    int n0 = blockIdx.x * TILE;
    const float* Ab = A + (long)b * aStride;
    const float* Bb = Bm + (long)b * bStride;
    float*       Cb = C + (long)b * cStride;

    __shared__ float As[KC][TILE];
    __shared__ float Bs[KC][TILE];

    int tid = threadIdx.x;
    int tx4 = (tid & 15) << 2;
    int ty4 = (tid >> 4) << 2;
    int lr  = tid >> 2;
    int lc4 = (tid & 3) << 2;
    int br  = tid >> 4;
    int bc4 = (tid & 15) << 2;

    float acc[4][4] = {};

    for (int k0 = 0; k0 < K; k0 += KC) {
        float4 av = *(const float4*)(Ab + (long)(m0 + lr) * K + k0 + lc4);
        As[lc4 + 0][lr] = av.x;
        As[lc4 + 1][lr] = av.y;
        As[lc4 + 2][lr] = av.z;
        As[lc4 + 3][lr] = av.w;
        int cc = n0 + bc4;
        float4 bv = make_float4(0.f, 0.f, 0.f, 0.f);
        const float* bp = Bb + (long)(k0 + br) * Nn + cc;
        if (cc + 3 < Nn) {
            bv = *(const float4*)bp;
        } else {
            if (cc + 0 < Nn) bv.x = bp[0];
            if (cc + 1 < Nn) bv.y = bp[1];
            if (cc + 2 < Nn) bv.z = bp[2];
            if (cc + 3 < Nn) bv.w = bp[3];
        }
        *(float4*)&Bs[br][bc4] = bv;
        __syncthreads();
#pragma unroll
        for (int kk = 0; kk < KC; ++kk) {
            float4 a  = *(const float4*)&As[kk][ty4];
            float4 bq = *(const float4*)&Bs[kk][tx4];
            acc[0][0] += a.x * bq.x; acc[0][1] += a.x * bq.y;
            acc[0][2] += a.x * bq.z; acc[0][3] += a.x * bq.w;
            acc[1][0] += a.y * bq.x; acc[1][1] += a.y * bq.y;
            acc[1][2] += a.y * bq.z; acc[1][3] += a.y * bq.w;
            acc[2][0] += a.z * bq.x; acc[2][1] += a.z * bq.y;
            acc[2][2] += a.z * bq.z; acc[2][3] += a.z * bq.w;
            acc[3][0] += a.w * bq.x; acc[3][1] += a.w * bq.y;
            acc[3][2] += a.w * bq.z; acc[3][3] += a.w * bq.w;
        }
        __syncthreads();
    }

#pragma unroll
    for (int i = 0; i < 4; ++i) {
        int r = m0 + ty4 + i;
#pragma unroll
        for (int j = 0; j < 4; ++j) {
            int c = n0 + tx4 + j;
            if (c < Nn)
                Cb[(long)r * Nn + c] = acc[i][j] + (bias ? bias[c] : 0.f);
        }
    }
}

// --------------------------------------------------------------------------
extern "C" void kernel_launch(void* const* d_in, const int* in_sizes, int n_in,
                              void* d_out, int out_size, void* d_ws, size_t ws_size,
                              hipStream_t stream) {
    const float* obs    = (const float*)d_in[0];
    const int*   hyper  = (const int*)d_in[1];
    const float* Wenc   = (const float*)d_in[2];
    const float* benc   = (const float*)d_in[3];
    const float* thetas = (const float*)d_in[4];
    const float* convb  = (const float*)d_in[5];
    const float* gammas = (const float*)d_in[6];
    const float* betas  = (const float*)d_in[7];
    const float* Wdec   = (const float*)d_in[8];
    const float* bdec   = (const float*)d_in[9];
    float* out = (float*)d_out;

    char* w = (char*)d_ws;
    auto alloc = [&](size_t bytes) { char* p = w; w += (bytes + 255) & ~255ULL; return p; };
    float* hT    = (float*)alloc((size_t)B_ * H_ * N_ * 4);
    float* comb  = (float*)alloc((size_t)B_ * N_ * H_ * 4);
    float* DinvN = (float*)alloc((size_t)B_ * N_ * 4);
    float* BinvM = (float*)alloc((size_t)B_ * M_ * 4);
    unsigned short* Hmat  = (unsigned short*)alloc((size_t)B_ * N_ * M_ * 2);
    unsigned short* HmatT = (unsigned short*)alloc((size_t)B_ * M_ * N_ * 2);
    unsigned short* actA  = (unsigned short*)alloc((size_t)B_ * H_ * N_ * 2 * 2);
    unsigned short* actB  = (unsigned short*)alloc((size_t)B_ * H_ * N_ * 2 * 2);
    unsigned short* thT   = (unsigned short*)alloc((size_t)L_ * H_ * H_ * 2 * 2);

    const long actLo = (long)B_ * H_ * N_;
    const long thLo  = (long)L_ * H_ * H_;

    hipMemsetAsync(BinvM, 0, (size_t)B_ * M_ * 4, stream);
    encoder3_kernel<<<dim3(B_, 4), 512, 0, stream>>>(obs, Wenc, benc, hT, actA, actLo);
    build_kernel<<<dim3(B_, 8), 256, 0, stream>>>(hyper, Hmat, HmatT, DinvN, BinvM);
    inv_kernel<<<(B_ * M_ + 255) / 256, 256, 0, stream>>>(BinvM, B_ * M_);
    transpose_f32_bf16split<<<dim3(4, 4, 3), 256, 0, stream>>>(
        thetas, (long)H_ * H_, thT, (long)H_ * H_, thLo, H_, H_);

    const unsigned short* cur = actA;
    unsigned short* nxt = actB;
    for (int l = 0; l < L_; ++l) {
        layer_kernel<<<dim3(4, B_), 512, 0, stream>>>(
            HmatT, Hmat, cur, actLo, thT + (size_t)l * H_ * H_, thLo,
            BinvM, DinvN, convb + (size_t)l * H_,
            gammas + (size_t)l * H_, betas + (size_t)l * H_, nxt);
        const unsigned short* t = cur; cur = nxt; nxt = (unsigned short*)t;
    }
    // comb = h + h_social  (cur holds final activations)
    comb_transpose_kernel<<<dim3(8, 4, B_), 256, 0, stream>>>(cur, actLo, hT, comb);
    // out = comb @ Wdec + bdec (fp32)
    gemm_kernel<<<dim3(1, N_ / TILE, B_), 256, 0, stream>>>(
        comb, (long)N_ * H_, Wdec, 0,
        out, (long)N_ * P2_, N_, P2_, H_, bdec);
}

// Round 9
// 269.421 us; speedup vs baseline: 1.6864x; 1.0546x over previous
//
#include <hip/hip_runtime.h>
#include <hip/hip_bf16.h>

#define B_   64
#define N_   512
#define T_   8
#define DIN_ 2
#define H_   256
#define L_   3
#define E_   8192
#define M_   128
#define P2_  24   // P*2
#define EPS_ 1e-5f

#define TILE 64
#define KC   16
#define WTPAD 136

typedef __attribute__((ext_vector_type(8))) short short8;
typedef __attribute__((ext_vector_type(4))) float floatx4;

__device__ __forceinline__ unsigned short f2bf(float f) {
    union { float f; unsigned u; } v; v.f = f;
    unsigned r = v.u + 0x7FFF + ((v.u >> 16) & 1);
    return (unsigned short)(r >> 16);
}
__device__ __forceinline__ float bf2f(unsigned short h) {
    union { unsigned u; float f; } v; v.u = (unsigned)h << 16; return v.f;
}

// ===== prep: encoder (256 blks) + incidence build (512 blks) + thetaT (48) ==
__global__ __launch_bounds__(512, 2) void prep_kernel(
    const float* __restrict__ obs, const float* __restrict__ Wenc,
    const float* __restrict__ benc, float* __restrict__ hT,
    unsigned short* __restrict__ actT, long actLo,
    const int* __restrict__ idx, unsigned short* __restrict__ Hmat,
    unsigned short* __restrict__ HmatT, float* __restrict__ DinvN,
    float* __restrict__ degM,
    const float* __restrict__ thetas, unsigned short* __restrict__ thT, long thLo)
{
    __shared__ __align__(16) char u[33024];
    int bid = blockIdx.x, tid = threadIdx.x;
    if (bid < 256) {
        // ---------------- encoder role ----------------
        float* ot = (float*)u;   // [16][513]
        int b = bid >> 2, h0 = (bid & 3) * 64;
        const float4* src = (const float4*)(obs + (long)b * N_ * 16);
        for (int i = tid; i < 2048; i += 512) {
            float4 v = src[i];
            int n = i >> 2, k4 = (i & 3) << 2;
            ot[(k4 + 0) * 513 + n] = v.x;
            ot[(k4 + 1) * 513 + n] = v.y;
            ot[(k4 + 2) * 513 + n] = v.z;
            ot[(k4 + 3) * 513 + n] = v.w;
        }
        __syncthreads();
        int wave = tid >> 6, lane = tid & 63;
        int cbase = h0 + wave * 8;
        float w0[8], w1[8], bb[8];
#pragma unroll
        for (int i = 0; i < 8; ++i) {
            w0[i] = Wenc[cbase + i];
            w1[i] = Wenc[H_ + cbase + i];
            bb[i] = benc[cbase + i];
        }
        for (int j = 0; j < 8; ++j) {
            int n = j * 64 + lane;
            float x0[8], x1[8];
#pragma unroll
            for (int t = 0; t < 8; ++t) {
                x0[t] = ot[(2 * t) * 513 + n];
                x1[t] = ot[(2 * t + 1) * 513 + n];
            }
#pragma unroll
            for (int i = 0; i < 8; ++i) {
                float acc = 0.f;
#pragma unroll
                for (int t = 0; t < 8; ++t)
                    acc += fmaxf(x0[t] * w0[i] + x1[t] * w1[i] + bb[i], 0.f);
                acc *= 0.125f;
                long o = ((long)b * H_ + cbase + i) * N_ + n;
                hT[o] = acc;
                unsigned short hv = f2bf(acc);
                actT[o] = hv;
                actT[actLo + o] = f2bf(acc - bf2f(hv));
            }
        }
    } else if (bid < 768) {
        // ---------------- build role ----------------
        unsigned* cnt = (unsigned*)u;    // [64][129]
        int id2 = bid - 256;
        int b = id2 >> 3, chunk = id2 & 7;
        int c0 = chunk * 64;
        for (int i = tid; i < 64 * 129; i += 512) cnt[i] = 0;
        __syncthreads();
        const int* nodes = idx + (long)b * 2 * E_;
        const int* edges = nodes + E_;
        for (int e = tid; e < E_; e += 512) {
            int n = nodes[e];
            if ((n >> 6) == chunk) atomicAdd(&cnt[(n & 63) * 129 + edges[e]], 1u);
        }
        __syncthreads();
        for (int i = tid; i < 64 * 128; i += 512) {
            int r = i >> 7, m = i & 127;
            Hmat[((long)(b * N_ + c0 + r)) * M_ + m] = f2bf((float)cnt[r * 129 + m]);
        }
        for (int i = tid; i < 64 * 128; i += 512) {
            int m = i >> 6, r = i & 63;
            HmatT[((long)(b * M_ + m)) * N_ + c0 + r] = f2bf((float)cnt[r * 129 + m]);
        }
        if (tid < 64) {
            unsigned s = 0;
#pragma unroll 8
            for (int m = 0; m < 128; ++m) s += cnt[tid * 129 + m];
            DinvN[b * N_ + c0 + tid] = 1.0f / fmaxf((float)s, 1.0f);
        } else if (tid < 192) {
            int m = tid - 64;
            unsigned s = 0;
#pragma unroll 8
            for (int r = 0; r < 64; ++r) s += cnt[r * 129 + m];
            atomicAdd(&degM[b * M_ + m], (float)s);
        }
    } else {
        // ---------------- thetaT split-bf16 transpose role ----------------
        float (*tile)[65] = (float(*)[65])u;
        int sub = bid - 768;                 // 0..47
        int cx = sub & 3, ry = (sub >> 2) & 3, l = sub >> 4;
        int r0 = ry * 64, c0 = cx * 64;
        const float* ib = thetas + (long)l * H_ * H_;
        unsigned short* ob = thT + (long)l * H_ * H_;
        int x = tid & 63, y0 = tid >> 6;     // y0: 0..7
#pragma unroll
        for (int i = 0; i < 8; ++i) {
            int y = y0 * 8 + i;
            tile[y][x] = ib[(long)(r0 + y) * H_ + c0 + x];
        }
        __syncthreads();
#pragma unroll
        for (int i = 0; i < 8; ++i) {
            int y = y0 * 8 + i;
            float v = tile[x][y];
            unsigned short hv = f2bf(v);
            long o = (long)(c0 + y) * H_ + r0 + x;
            ob[o] = hv;
            ob[thLo + o] = f2bf(v - bf2f(hv));
        }
    }
}

// ===== z: Z[m][h'] = (1/max(degM,1)) * sum_n HT[m][n]*act[h'][n], split out ==
// grid (64, 2): block (b, half) computes cols hs..hs+127. id%8 = b%8 (XCD).
__global__ __launch_bounds__(256, 2) void z_kernel(
    const unsigned short* __restrict__ HmatT,
    const unsigned short* __restrict__ actIn, long actLo,
    const float* __restrict__ degM,
    unsigned short* __restrict__ Zg, long zLo)
{
    __shared__ __align__(16) unsigned short As1[128 * 40];
    __shared__ __align__(16) unsigned short Bh[128 * 40];
    __shared__ __align__(16) unsigned short Bl[128 * 40];
    int b = blockIdx.x, hs = blockIdx.y * 128;
    int tid = threadIdx.x, wave = tid >> 6, lane = tid & 63;
    int lr = lane & 15, lq = lane >> 4;
    int wm = (wave & 1) * 64, wn = (wave >> 1) * 64;
    const unsigned short* HT   = HmatT + (long)b * M_ * N_;
    const unsigned short* aInH = actIn + (long)b * H_ * N_ + (long)hs * N_;
    const unsigned short* aInL = actIn + actLo + (long)b * H_ * N_ + (long)hs * N_;

    floatx4 acc[4][4] = {};
    int r0 = tid >> 2, ck = (tid & 3) << 3;
    int r1 = (tid + 256) >> 2;
    uint4 pA0  = *(const uint4*)&HT[(long)r0 * N_ + ck];
    uint4 pA1  = *(const uint4*)&HT[(long)r1 * N_ + ck];
    uint4 pBh0 = *(const uint4*)&aInH[(long)r0 * N_ + ck];
    uint4 pBh1 = *(const uint4*)&aInH[(long)r1 * N_ + ck];
    uint4 pBl0 = *(const uint4*)&aInL[(long)r0 * N_ + ck];
    uint4 pBl1 = *(const uint4*)&aInL[(long)r1 * N_ + ck];
    for (int k0 = 0; k0 < N_; k0 += 32) {
        __syncthreads();
        *(uint4*)&As1[r0 * 40 + ck] = pA0;
        *(uint4*)&As1[r1 * 40 + ck] = pA1;
        *(uint4*)&Bh[r0 * 40 + ck]  = pBh0;
        *(uint4*)&Bh[r1 * 40 + ck]  = pBh1;
        *(uint4*)&Bl[r0 * 40 + ck]  = pBl0;
        *(uint4*)&Bl[r1 * 40 + ck]  = pBl1;
        __syncthreads();
        int kn = k0 + 32;
        if (kn < N_) {
            pA0  = *(const uint4*)&HT[(long)r0 * N_ + kn + ck];
            pA1  = *(const uint4*)&HT[(long)r1 * N_ + kn + ck];
            pBh0 = *(const uint4*)&aInH[(long)r0 * N_ + kn + ck];
            pBh1 = *(const uint4*)&aInH[(long)r1 * N_ + kn + ck];
            pBl0 = *(const uint4*)&aInL[(long)r0 * N_ + kn + ck];
            pBl1 = *(const uint4*)&aInL[(long)r1 * N_ + kn + ck];
        }
        short8 af[4], bh[4], bl[4];
#pragma unroll
        for (int mt = 0; mt < 4; ++mt)
            af[mt] = *(const short8*)&As1[(wm + mt * 16 + lr) * 40 + lq * 8];
#pragma unroll
        for (int nt = 0; nt < 4; ++nt) {
            bh[nt] = *(const short8*)&Bh[(wn + nt * 16 + lr) * 40 + lq * 8];
            bl[nt] = *(const short8*)&Bl[(wn + nt * 16 + lr) * 40 + lq * 8];
        }
#pragma unroll
        for (int mt = 0; mt < 4; ++mt)
#pragma unroll
            for (int nt = 0; nt < 4; ++nt) {
                acc[mt][nt] = __builtin_amdgcn_mfma_f32_16x16x32_bf16(
                    af[mt], bh[nt], acc[mt][nt], 0, 0, 0);
                acc[mt][nt] = __builtin_amdgcn_mfma_f32_16x16x32_bf16(
                    af[mt], bl[nt], acc[mt][nt], 0, 0, 0);
            }
    }
#pragma unroll
    for (int mt = 0; mt < 4; ++mt)
#pragma unroll
        for (int r4 = 0; r4 < 4; ++r4) {
            int m = wm + mt * 16 + lq * 4 + r4;
            float rsB = 1.0f / fmaxf(degM[b * M_ + m], 1.0f);
#pragma unroll
            for (int nt = 0; nt < 4; ++nt) {
                float v = acc[mt][nt][r4] * rsB;
                unsigned short hv = f2bf(v);
                long o = ((long)b * M_ + m) * H_ + hs + wn + nt * 16 + lr;
                Zg[o] = hv;
                Zg[zLo + o] = f2bf(v - bf2f(hv));
            }
        }
}

// ===== wh: W=Theta^T Z^T ; hc^T=Dinv(W Hm^T)+cb ; BN ; ReLU ; split write ==
__global__ __launch_bounds__(512, 2) void wh_kernel(
    const unsigned short* __restrict__ Zg, long zLo,
    const unsigned short* __restrict__ Hmat,
    const unsigned short* __restrict__ thT, long thLo,   // pre-offset to layer
    const float* __restrict__ DinvN, const float* __restrict__ convb,
    const float* __restrict__ gamma, const float* __restrict__ beta,
    unsigned short* __restrict__ actOut, long actLo)
{
    __shared__ __align__(16) char lds[39424];
    unsigned short* Zch  = (unsigned short*)lds;            // [128][40]
    unsigned short* Zcl  = Zch + 128 * 40;
    unsigned short* As2h = Zcl + 128 * 40;                  // [64][40]
    unsigned short* As2l = As2h + 64 * 40;
    unsigned short* Wh   = (unsigned short*)lds;            // [64][136] overlap
    unsigned short* Wl   = Wh + 64 * WTPAD;
    float* rsum = (float*)(lds + 64 * WTPAD * 2 * 2);       // [64][8]
    float* rsq  = rsum + 512;
    float2* prm = (float2*)(rsq + 512);                     // [64]

    // XCD swizzle: batch b's 4 chunks all land on XCD b%8
    int id = blockIdx.x + (blockIdx.y << 2);
    int xcd = id & 7, slot = id >> 3;
    int b  = ((slot >> 2) << 3) + xcd;
    int h0 = (slot & 3) * 64;

    int tid = threadIdx.x, wave = tid >> 6, lane = tid & 63;
    int lr = lane & 15, lq = lane >> 4;
    const unsigned short* Zb = Zg + (long)b * M_ * H_;
    const unsigned short* Hm = Hmat + (long)b * N_ * M_;

    // ---- stage 2: W[h][m] = sum_h' thT[h][h'] * Z[m][h'] (3-pass split) ----
    int wm2 = (wave >> 2) * 32, wn2 = (wave & 3) * 32;
    int i2 = tid & 255, pl2 = tid >> 8;
    int r2 = i2 >> 2, ck2 = (i2 & 3) << 3;
    const unsigned short* thBase = thT + (pl2 ? thLo : 0) + (long)(h0 + r2) * H_ + ck2;
    unsigned short* As2dst = (pl2 ? As2l : As2h) + r2 * 40 + ck2;
    int rz = tid >> 2, ckz = (tid & 3) << 3;
    uint4 pTh = *(const uint4*)thBase;
    uint4 pZh = *(const uint4*)&Zb[(long)rz * H_ + ckz];
    uint4 pZl = *(const uint4*)&Zb[zLo + (long)rz * H_ + ckz];
    floatx4 acc2[2][2] = {};
    for (int k0 = 0; k0 < H_; k0 += 32) {
        __syncthreads();
        *(uint4*)As2dst = pTh;
        *(uint4*)&Zch[rz * 40 + ckz] = pZh;
        *(uint4*)&Zcl[rz * 40 + ckz] = pZl;
        __syncthreads();
        int kn = k0 + 32;
        if (kn < H_) {
            pTh = *(const uint4*)(thBase + kn);
            pZh = *(const uint4*)&Zb[(long)rz * H_ + kn + ckz];
            pZl = *(const uint4*)&Zb[zLo + (long)rz * H_ + kn + ckz];
        }
        short8 ah[2], al[2], zb[2], zl[2];
#pragma unroll
        for (int mt = 0; mt < 2; ++mt) {
            ah[mt] = *(const short8*)&As2h[(wm2 + mt * 16 + lr) * 40 + lq * 8];
            al[mt] = *(const short8*)&As2l[(wm2 + mt * 16 + lr) * 40 + lq * 8];
        }
#pragma unroll
        for (int nt = 0; nt < 2; ++nt) {
            zb[nt] = *(const short8*)&Zch[(wn2 + nt * 16 + lr) * 40 + lq * 8];
            zl[nt] = *(const short8*)&Zcl[(wn2 + nt * 16 + lr) * 40 + lq * 8];
        }
#pragma unroll
        for (int mt = 0; mt < 2; ++mt)
#pragma unroll
            for (int nt = 0; nt < 2; ++nt) {
                acc2[mt][nt] = __builtin_amdgcn_mfma_f32_16x16x32_bf16(
                    ah[mt], zb[nt], acc2[mt][nt], 0, 0, 0);
                acc2[mt][nt] = __builtin_amdgcn_mfma_f32_16x16x32_bf16(
                    ah[mt], zl[nt], acc2[mt][nt], 0, 0, 0);
                acc2[mt][nt] = __builtin_amdgcn_mfma_f32_16x16x32_bf16(
                    al[mt], zb[nt], acc2[mt][nt], 0, 0, 0);
            }
    }
    __syncthreads();
#pragma unroll
    for (int mt = 0; mt < 2; ++mt)
#pragma unroll
        for (int r4 = 0; r4 < 4; ++r4) {
            int row = wm2 + mt * 16 + lq * 4 + r4;
#pragma unroll
            for (int nt = 0; nt < 2; ++nt) {
                int col = wn2 + nt * 16 + lr;
                float v = acc2[mt][nt][r4];
                unsigned short hv = f2bf(v);
                Wh[row * WTPAD + col] = hv;
                Wl[row * WTPAD + col] = f2bf(v - bf2f(hv));
            }
        }
    __syncthreads();

    // ---- stage 3: hc^T[h][n] = Dinv[n]*sum_m W[h][m]*Hm[n][m] + cb --------
    int wn3 = wave * 64;
    floatx4 acc3[4][4] = {};
    for (int k0 = 0; k0 < M_; k0 += 32) {
        short8 ah[4], al[4], bh3[4];
#pragma unroll
        for (int nt = 0; nt < 4; ++nt)
            bh3[nt] = *(const short8*)&Hm[(long)(wn3 + nt * 16 + lr) * M_ + k0 + lq * 8];
#pragma unroll
        for (int mt = 0; mt < 4; ++mt) {
            ah[mt] = *(const short8*)&Wh[(mt * 16 + lr) * WTPAD + k0 + lq * 8];
            al[mt] = *(const short8*)&Wl[(mt * 16 + lr) * WTPAD + k0 + lq * 8];
        }
#pragma unroll
        for (int mt = 0; mt < 4; ++mt)
#pragma unroll
            for (int nt = 0; nt < 4; ++nt) {
                acc3[mt][nt] = __builtin_amdgcn_mfma_f32_16x16x32_bf16(
                    ah[mt], bh3[nt], acc3[mt][nt], 0, 0, 0);
                acc3[mt][nt] = __builtin_amdgcn_mfma_f32_16x16x32_bf16(
                    al[mt], bh3[nt], acc3[mt][nt], 0, 0, 0);
            }
    }

    float dv[4];
#pragma unroll
    for (int nt = 0; nt < 4; ++nt)
        dv[nt] = DinvN[b * N_ + wn3 + nt * 16 + lr];
    float cb[4][4];
#pragma unroll
    for (int mt = 0; mt < 4; ++mt)
#pragma unroll
        for (int r4 = 0; r4 < 4; ++r4)
            cb[mt][r4] = convb[h0 + mt * 16 + lq * 4 + r4];
#pragma unroll
    for (int mt = 0; mt < 4; ++mt)
#pragma unroll
        for (int nt = 0; nt < 4; ++nt)
#pragma unroll
            for (int r4 = 0; r4 < 4; ++r4)
                acc3[mt][nt][r4] = acc3[mt][nt][r4] * dv[nt] + cb[mt][r4];

    float ps[4][4], pq[4][4];
#pragma unroll
    for (int mt = 0; mt < 4; ++mt)
#pragma unroll
        for (int r4 = 0; r4 < 4; ++r4) {
            float s = 0.f, q = 0.f;
#pragma unroll
            for (int nt = 0; nt < 4; ++nt) {
                float v = acc3[mt][nt][r4];
                s += v; q += v * v;
            }
            ps[mt][r4] = s; pq[mt][r4] = q;
        }
#pragma unroll
    for (int mask = 1; mask <= 8; mask <<= 1) {
#pragma unroll
        for (int mt = 0; mt < 4; ++mt)
#pragma unroll
            for (int r4 = 0; r4 < 4; ++r4) {
                ps[mt][r4] += __shfl_xor(ps[mt][r4], mask);
                pq[mt][r4] += __shfl_xor(pq[mt][r4], mask);
            }
    }
    if (lr == 0) {
#pragma unroll
        for (int mt = 0; mt < 4; ++mt)
#pragma unroll
            for (int r4 = 0; r4 < 4; ++r4) {
                int row = mt * 16 + lq * 4 + r4;
                rsum[row * 8 + wave] = ps[mt][r4];
                rsq[row * 8 + wave]  = pq[mt][r4];
            }
    }
    __syncthreads();
    if (tid < 64) {
        float s = 0.f, s2 = 0.f;
#pragma unroll
        for (int w = 0; w < 8; ++w) { s += rsum[tid * 8 + w]; s2 += rsq[tid * 8 + w]; }
        float mu  = s * (1.0f / N_);
        float var = fmaxf(s2 * (1.0f / N_) - mu * mu, 0.f);
        float sc  = gamma[h0 + tid] * rsqrtf(var + EPS_);
        prm[tid] = make_float2(sc, beta[h0 + tid] - mu * sc);
    }
    __syncthreads();

    unsigned short* ab = actOut + (long)b * H_ * N_;
#pragma unroll
    for (int mt = 0; mt < 4; ++mt)
#pragma unroll
        for (int r4 = 0; r4 < 4; ++r4) {
            int row = mt * 16 + lq * 4 + r4;
            float2 p = prm[row];
#pragma unroll
            for (int nt = 0; nt < 4; ++nt) {
                float y = fmaxf(acc3[mt][nt][r4] * p.x + p.y, 0.f);
                unsigned short hv = f2bf(y);
                long o = (long)(h0 + row) * N_ + wn3 + nt * 16 + lr;
                ab[o] = hv;
                ab[actLo + o] = f2bf(y - bf2f(hv));
            }
        }
}

// ---- comb[n][h] = hT[h][n] + actT[h][n] (hi+lo), fp32 --------------------
__global__ __launch_bounds__(256) void comb_transpose_kernel(
    const unsigned short* __restrict__ actT, long actLo,
    const float* __restrict__ hT, float* __restrict__ comb)
{
    int b  = blockIdx.z;
    int n0 = blockIdx.x * 64, h0 = blockIdx.y * 64;
    __shared__ float tile[64][65];
    const unsigned short* ab = actT + (long)b * H_ * N_;
    const float* hb = hT + (long)b * H_ * N_;
    int x = threadIdx.x & 63, y0 = threadIdx.x >> 6;
#pragma unroll
    for (int i = 0; i < 16; ++i) {
        int y = y0 * 16 + i;
        long o = (long)(h0 + y) * N_ + n0 + x;
        tile[y][x] = bf2f(ab[o]) + bf2f(ab[actLo + o]) + hb[o];
    }
    __syncthreads();
#pragma unroll
    for (int i = 0; i < 16; ++i) {
        int y = y0 * 16 + i;
        comb[((long)b * N_ + n0 + y) * H_ + h0 + x] = tile[x][y];
    }
}

// -------------------- fp32 tiled GEMM (decoder only) ----------------------
__global__ __launch_bounds__(256) void gemm_kernel(
    const float* __restrict__ A, long aStride,
    const float* __restrict__ Bm, long bStride,
    float* __restrict__ C, long cStride,
    int M, int Nn, int K,
    const float* __restrict__ bias)
{
    int b  = blockIdx.z;
    int m0 = blockIdx.y * TILE;
    int n0 = blockIdx.x * TILE;
    const float* Ab = A + (long)b * aStride;
    const float* Bb = Bm + (long)b * bStride;
    float*       Cb = C + (long)b * cStride;

    __shared__ float As[KC][TILE];
    __shared__ float Bs[KC][TILE];

    int tid = threadIdx.x;
    int tx4 = (tid & 15) << 2;
    int ty4 = (tid >> 4) << 2;
    int lr  = tid >> 2;
    int lc4 = (tid & 3) << 2;
    int br  = tid >> 4;
    int bc4 = (tid & 15) << 2;

    float acc[4][4] = {};

    for (int k0 = 0; k0 < K; k0 += KC) {
        float4 av = *(const float4*)(Ab + (long)(m0 + lr) * K + k0 + lc4);
        As[lc4 + 0][lr] = av.x;
        As[lc4 + 1][lr] = av.y;
        As[lc4 + 2][lr] = av.z;
        As[lc4 + 3][lr] = av.w;
        int cc = n0 + bc4;
        float4 bv = make_float4(0.f, 0.f, 0.f, 0.f);
        const float* bp = Bb + (long)(k0 + br) * Nn + cc;
        if (cc + 3 < Nn) {
            bv = *(const float4*)bp;
        } else {
            if (cc + 0 < Nn) bv.x = bp[0];
            if (cc + 1 < Nn) bv.y = bp[1];
            if (cc + 2 < Nn) bv.z = bp[2];
            if (cc + 3 < Nn) bv.w = bp[3];
        }
        *(float4*)&Bs[br][bc4] = bv;
        __syncthreads();
#pragma unroll
        for (int kk = 0; kk < KC; ++kk) {
            float4 a  = *(const float4*)&As[kk][ty4];
            float4 bq = *(const float4*)&Bs[kk][tx4];
            acc[0][0] += a.x * bq.x; acc[0][1] += a.x * bq.y;
            acc[0][2] += a.x * bq.z; acc[0][3] += a.x * bq.w;
            acc[1][0] += a.y * bq.x; acc[1][1] += a.y * bq.y;
            acc[1][2] += a.y * bq.z; acc[1][3] += a.y * bq.w;
            acc[2][0] += a.z * bq.x; acc[2][1] += a.z * bq.y;
            acc[2][2] += a.z * bq.z; acc[2][3] += a.z * bq.w;
            acc[3][0] += a.w * bq.x; acc[3][1] += a.w * bq.y;
            acc[3][2] += a.w * bq.z; acc[3][3] += a.w * bq.w;
        }
        __syncthreads();
    }

#pragma unroll
    for (int i = 0; i < 4; ++i) {
        int r = m0 + ty4 + i;
#pragma unroll
        for (int j = 0; j < 4; ++j) {
            int c = n0 + tx4 + j;
            if (c < Nn)
                Cb[(long)r * Nn + c] = acc[i][j] + (bias ? bias[c] : 0.f);
        }
    }
}

// --------------------------------------------------------------------------
extern "C" void kernel_launch(void* const* d_in, const int* in_sizes, int n_in,
                              void* d_out, int out_size, void* d_ws, size_t ws_size,
                              hipStream_t stream) {
    const float* obs    = (const float*)d_in[0];
    const int*   hyper  = (const int*)d_in[1];
    const float* Wenc   = (const float*)d_in[2];
    const float* benc   = (const float*)d_in[3];
    const float* thetas = (const float*)d_in[4];
    const float* convb  = (const float*)d_in[5];
    const float* gammas = (const float*)d_in[6];
    const float* betas  = (const float*)d_in[7];
    const float* Wdec   = (const float*)d_in[8];
    const float* bdec   = (const float*)d_in[9];
    float* out = (float*)d_out;

    char* w = (char*)d_ws;
    auto alloc = [&](size_t bytes) { char* p = w; w += (bytes + 255) & ~255ULL; return p; };
    float* hT    = (float*)alloc((size_t)B_ * H_ * N_ * 4);
    float* comb  = (float*)alloc((size_t)B_ * N_ * H_ * 4);
    float* DinvN = (float*)alloc((size_t)B_ * N_ * 4);
    float* degM  = (float*)alloc((size_t)B_ * M_ * 4);
    unsigned short* Hmat  = (unsigned short*)alloc((size_t)B_ * N_ * M_ * 2);
    unsigned short* HmatT = (unsigned short*)alloc((size_t)B_ * M_ * N_ * 2);
    unsigned short* actA  = (unsigned short*)alloc((size_t)B_ * H_ * N_ * 2 * 2);
    unsigned short* actB  = (unsigned short*)alloc((size_t)B_ * H_ * N_ * 2 * 2);
    unsigned short* thT   = (unsigned short*)alloc((size_t)L_ * H_ * H_ * 2 * 2);
    unsigned short* Zg    = (unsigned short*)alloc((size_t)B_ * M_ * H_ * 2 * 2);

    const long actLo = (long)B_ * H_ * N_;
    const long thLo  = (long)L_ * H_ * H_;
    const long zLo   = (long)B_ * M_ * H_;

    hipMemsetAsync(degM, 0, (size_t)B_ * M_ * 4, stream);
    prep_kernel<<<816, 512, 0, stream>>>(
        obs, Wenc, benc, hT, actA, actLo,
        hyper, Hmat, HmatT, DinvN, degM,
        thetas, thT, thLo);

    const unsigned short* cur = actA;
    unsigned short* nxt = actB;
    for (int l = 0; l < L_; ++l) {
        z_kernel<<<dim3(B_, 2), 256, 0, stream>>>(
            HmatT, cur, actLo, degM, Zg, zLo);
        wh_kernel<<<dim3(4, B_), 512, 0, stream>>>(
            Zg, zLo, Hmat, thT + (size_t)l * H_ * H_, thLo,
            DinvN, convb + (size_t)l * H_,
            gammas + (size_t)l * H_, betas + (size_t)l * H_, nxt, actLo);
        const unsigned short* t = cur; cur = nxt; nxt = (unsigned short*)t;
    }
    // comb = h + h_social  (cur holds final activations)
    comb_transpose_kernel<<<dim3(8, 4, B_), 256, 0, stream>>>(cur, actLo, hT, comb);
    // out = comb @ Wdec + bdec (fp32)
    gemm_kernel<<<dim3(1, N_ / TILE, B_), 256, 0, stream>>>(
        comb, (long)N_ * H_, Wdec, 0,
        out, (long)N_ * P2_, N_, P2_, H_, bdec);
}

// Round 10
// 228.961 us; speedup vs baseline: 1.9844x; 1.1767x over previous
//
#include <hip/hip_runtime.h>
#include <hip/hip_bf16.h>

#define B_   64
#define N_   512
#define T_   8
#define DIN_ 2
#define H_   256
#define L_   3
#define E_   8192
#define M_   128
#define P2_  24   // P*2
#define EPS_ 1e-5f

#define WTPAD 136

typedef __attribute__((ext_vector_type(8))) short short8;
typedef __attribute__((ext_vector_type(4))) float floatx4;

__device__ __forceinline__ unsigned short f2bf(float f) {
    union { float f; unsigned u; } v; v.f = f;
    unsigned r = v.u + 0x7FFF + ((v.u >> 16) & 1);
    return (unsigned short)(r >> 16);
}
__device__ __forceinline__ float bf2f(unsigned short h) {
    union { unsigned u; float f; } v; v.u = (unsigned)h << 16; return v.f;
}

// ===== prep: encoder (256 blks) + incidence build (512 blks) + thetaT (48) ==
__global__ __launch_bounds__(512, 2) void prep_kernel(
    const float* __restrict__ obs, const float* __restrict__ Wenc,
    const float* __restrict__ benc, float* __restrict__ hT,
    unsigned short* __restrict__ actT, long actLo,
    const int* __restrict__ idx, unsigned short* __restrict__ Hmat,
    unsigned short* __restrict__ HmatT, float* __restrict__ DinvN,
    float* __restrict__ degM,
    const float* __restrict__ thetas, unsigned short* __restrict__ thT, long thLo)
{
    __shared__ __align__(16) char u[33024];
    int bid = blockIdx.x, tid = threadIdx.x;
    if (bid < 256) {
        float* ot = (float*)u;   // [16][513]
        int b = bid >> 2, h0 = (bid & 3) * 64;
        const float4* src = (const float4*)(obs + (long)b * N_ * 16);
        for (int i = tid; i < 2048; i += 512) {
            float4 v = src[i];
            int n = i >> 2, k4 = (i & 3) << 2;
            ot[(k4 + 0) * 513 + n] = v.x;
            ot[(k4 + 1) * 513 + n] = v.y;
            ot[(k4 + 2) * 513 + n] = v.z;
            ot[(k4 + 3) * 513 + n] = v.w;
        }
        __syncthreads();
        int wave = tid >> 6, lane = tid & 63;
        int cbase = h0 + wave * 8;
        float w0[8], w1[8], bb[8];
#pragma unroll
        for (int i = 0; i < 8; ++i) {
            w0[i] = Wenc[cbase + i];
            w1[i] = Wenc[H_ + cbase + i];
            bb[i] = benc[cbase + i];
        }
        for (int j = 0; j < 8; ++j) {
            int n = j * 64 + lane;
            float x0[8], x1[8];
#pragma unroll
            for (int t = 0; t < 8; ++t) {
                x0[t] = ot[(2 * t) * 513 + n];
                x1[t] = ot[(2 * t + 1) * 513 + n];
            }
#pragma unroll
            for (int i = 0; i < 8; ++i) {
                float acc = 0.f;
#pragma unroll
                for (int t = 0; t < 8; ++t)
                    acc += fmaxf(x0[t] * w0[i] + x1[t] * w1[i] + bb[i], 0.f);
                acc *= 0.125f;
                long o = ((long)b * H_ + cbase + i) * N_ + n;
                hT[o] = acc;
                unsigned short hv = f2bf(acc);
                actT[o] = hv;
                actT[actLo + o] = f2bf(acc - bf2f(hv));
            }
        }
    } else if (bid < 768) {
        unsigned* cnt = (unsigned*)u;    // [64][129]
        int id2 = bid - 256;
        int b = id2 >> 3, chunk = id2 & 7;
        int c0 = chunk * 64;
        for (int i = tid; i < 64 * 129; i += 512) cnt[i] = 0;
        __syncthreads();
        const int* nodes = idx + (long)b * 2 * E_;
        const int* edges = nodes + E_;
        for (int e = tid; e < E_; e += 512) {
            int n = nodes[e];
            if ((n >> 6) == chunk) atomicAdd(&cnt[(n & 63) * 129 + edges[e]], 1u);
        }
        __syncthreads();
        for (int i = tid; i < 64 * 128; i += 512) {
            int r = i >> 7, m = i & 127;
            Hmat[((long)(b * N_ + c0 + r)) * M_ + m] = f2bf((float)cnt[r * 129 + m]);
        }
        for (int i = tid; i < 64 * 128; i += 512) {
            int m = i >> 6, r = i & 63;
            HmatT[((long)(b * M_ + m)) * N_ + c0 + r] = f2bf((float)cnt[r * 129 + m]);
        }
        if (tid < 64) {
            unsigned s = 0;
#pragma unroll 8
            for (int m = 0; m < 128; ++m) s += cnt[tid * 129 + m];
            DinvN[b * N_ + c0 + tid] = 1.0f / fmaxf((float)s, 1.0f);
        } else if (tid < 192) {
            int m = tid - 64;
            unsigned s = 0;
#pragma unroll 8
            for (int r = 0; r < 64; ++r) s += cnt[r * 129 + m];
            atomicAdd(&degM[b * M_ + m], (float)s);
        }
    } else {
        float (*tile)[65] = (float(*)[65])u;
        int sub = bid - 768;                 // 0..47
        int cx = sub & 3, ry = (sub >> 2) & 3, l = sub >> 4;
        int r0 = ry * 64, c0 = cx * 64;
        const float* ib = thetas + (long)l * H_ * H_;
        unsigned short* ob = thT + (long)l * H_ * H_;
        int x = tid & 63, y0 = tid >> 6;
#pragma unroll
        for (int i = 0; i < 8; ++i) {
            int y = y0 * 8 + i;
            tile[y][x] = ib[(long)(r0 + y) * H_ + c0 + x];
        }
        __syncthreads();
#pragma unroll
        for (int i = 0; i < 8; ++i) {
            int y = y0 * 8 + i;
            float v = tile[x][y];
            unsigned short hv = f2bf(v);
            long o = (long)(c0 + y) * H_ + r0 + x;
            ob[o] = hv;
            ob[thLo + o] = f2bf(v - bf2f(hv));
        }
    }
}

// ===== z: Z[m][h'] = (1/max(degM,1)) * sum_n HT[m][n]*act[h'][n], split out ==
// grid (64, 4): block (b, q) computes cols q*64..+63. id%8 = b%8 (XCD-local).
__global__ __launch_bounds__(256, 4) void z_kernel(
    const unsigned short* __restrict__ HmatT,
    const unsigned short* __restrict__ actIn, long actLo,
    const float* __restrict__ degM,
    unsigned short* __restrict__ Zg, long zLo)
{
    __shared__ __align__(16) unsigned short As1[128 * 40];
    __shared__ __align__(16) unsigned short Bh[64 * 40];
    __shared__ __align__(16) unsigned short Bl[64 * 40];
    int b = blockIdx.x, hs = blockIdx.y * 64;
    int tid = threadIdx.x, wave = tid >> 6, lane = tid & 63;
    int lr = lane & 15, lq = lane >> 4;
    int wm = (wave & 1) * 64, wn = (wave >> 1) * 32;
    const unsigned short* HT   = HmatT + (long)b * M_ * N_;
    const unsigned short* aInH = actIn + (long)b * H_ * N_ + (long)hs * N_;
    const unsigned short* aInL = actIn + actLo + (long)b * H_ * N_ + (long)hs * N_;

    floatx4 acc[4][2] = {};
    int r0 = tid >> 2, ck = (tid & 3) << 3;
    int r1 = r0 + 64;
    uint4 pA0 = *(const uint4*)&HT[(long)r0 * N_ + ck];
    uint4 pA1 = *(const uint4*)&HT[(long)r1 * N_ + ck];
    uint4 pBh = *(const uint4*)&aInH[(long)r0 * N_ + ck];
    uint4 pBl = *(const uint4*)&aInL[(long)r0 * N_ + ck];
    for (int k0 = 0; k0 < N_; k0 += 32) {
        __syncthreads();
        *(uint4*)&As1[r0 * 40 + ck] = pA0;
        *(uint4*)&As1[r1 * 40 + ck] = pA1;
        *(uint4*)&Bh[r0 * 40 + ck]  = pBh;
        *(uint4*)&Bl[r0 * 40 + ck]  = pBl;
        __syncthreads();
        int kn = k0 + 32;
        if (kn < N_) {
            pA0 = *(const uint4*)&HT[(long)r0 * N_ + kn + ck];
            pA1 = *(const uint4*)&HT[(long)r1 * N_ + kn + ck];
            pBh = *(const uint4*)&aInH[(long)r0 * N_ + kn + ck];
            pBl = *(const uint4*)&aInL[(long)r0 * N_ + kn + ck];
        }
        short8 af[4], bh[2], bl[2];
#pragma unroll
        for (int mt = 0; mt < 4; ++mt)
            af[mt] = *(const short8*)&As1[(wm + mt * 16 + lr) * 40 + lq * 8];
#pragma unroll
        for (int nt = 0; nt < 2; ++nt) {
            bh[nt] = *(const short8*)&Bh[(wn + nt * 16 + lr) * 40 + lq * 8];
            bl[nt] = *(const short8*)&Bl[(wn + nt * 16 + lr) * 40 + lq * 8];
        }
#pragma unroll
        for (int mt = 0; mt < 4; ++mt)
#pragma unroll
            for (int nt = 0; nt < 2; ++nt) {
                acc[mt][nt] = __builtin_amdgcn_mfma_f32_16x16x32_bf16(
                    af[mt], bh[nt], acc[mt][nt], 0, 0, 0);
                acc[mt][nt] = __builtin_amdgcn_mfma_f32_16x16x32_bf16(
                    af[mt], bl[nt], acc[mt][nt], 0, 0, 0);
            }
    }
#pragma unroll
    for (int mt = 0; mt < 4; ++mt)
#pragma unroll
        for (int r4 = 0; r4 < 4; ++r4) {
            int m = wm + mt * 16 + lq * 4 + r4;
            float rsB = 1.0f / fmaxf(degM[b * M_ + m], 1.0f);
#pragma unroll
            for (int nt = 0; nt < 2; ++nt) {
                float v = acc[mt][nt][r4] * rsB;
                unsigned short hv = f2bf(v);
                long o = ((long)b * M_ + m) * H_ + hs + wn + nt * 16 + lr;
                Zg[o] = hv;
                Zg[zLo + o] = f2bf(v - bf2f(hv));
            }
        }
}

// ===== wh: W=Theta^T Z^T ; hc^T=Dinv(W Hm^T)+cb ; BN ; ReLU ; split write ==
// grid 512 (1D): block = (batch, 32 h-rows). All 8 chunks of b on XCD b%8.
// 2 blocks/CU co-residency hides barriers.
__global__ __launch_bounds__(512, 4) void wh_kernel(
    const unsigned short* __restrict__ Zg, long zLo,
    const unsigned short* __restrict__ Hmat,
    const unsigned short* __restrict__ thT, long thLo,   // pre-offset to layer
    const float* __restrict__ DinvN, const float* __restrict__ convb,
    const float* __restrict__ gamma, const float* __restrict__ beta,
    unsigned short* __restrict__ actOut, long actLo)
{
    __shared__ __align__(16) char lds[28160];
    unsigned short* Zch  = (unsigned short*)lds;            // [128][40]
    unsigned short* Zcl  = Zch + 128 * 40;
    unsigned short* As2h = Zcl + 128 * 40;                  // [32][40]
    unsigned short* As2l = As2h + 32 * 40;                  // end 25600 B
    unsigned short* Wh   = (unsigned short*)lds;            // [32][136] overlap
    unsigned short* Wl   = Wh + 32 * WTPAD;                 // end 17408 B
    float* rsum = (float*)(lds + 25600);                    // [32][8]
    float* rsq  = rsum + 256;
    float2* prm = (float2*)(rsq + 256);                     // [32]

    int id = blockIdx.x;
    int xcd = id & 7, slot = id >> 3;
    int chunk = slot & 7;
    int b  = ((slot >> 3) << 3) | xcd;
    int h0 = chunk * 32;

    int tid = threadIdx.x, wave = tid >> 6, lane = tid & 63;
    int lr = lane & 15, lq = lane >> 4;
    const unsigned short* Zb = Zg + (long)b * M_ * H_;
    const unsigned short* Hm = Hmat + (long)b * N_ * M_;

    // ---- stage 2: W[h 32][m 128] = sum_h' thT[h][h'] * Z[m][h'] ----
    int wm2 = (wave >> 2) * 16, wn2 = (wave & 3) * 32;
    int i2 = tid & 255, pl2 = tid >> 8;
    int r2 = i2 >> 2, ck2 = (i2 & 3) << 3;   // active when i2 < 128 (r2 < 32)
    bool thAct = (i2 < 128);
    const unsigned short* thBase = thT + (pl2 ? thLo : 0) + (long)(h0 + r2) * H_ + ck2;
    unsigned short* As2dst = (pl2 ? As2l : As2h) + r2 * 40 + ck2;
    int rz = tid >> 2, ckz = (tid & 3) << 3;
    uint4 pTh = {};
    if (thAct) pTh = *(const uint4*)thBase;
    uint4 pZh = *(const uint4*)&Zb[(long)rz * H_ + ckz];
    uint4 pZl = *(const uint4*)&Zb[zLo + (long)rz * H_ + ckz];
    floatx4 acc2[2] = {};
    for (int k0 = 0; k0 < H_; k0 += 32) {
        __syncthreads();
        if (thAct) *(uint4*)As2dst = pTh;
        *(uint4*)&Zch[rz * 40 + ckz] = pZh;
        *(uint4*)&Zcl[rz * 40 + ckz] = pZl;
        __syncthreads();
        int kn = k0 + 32;
        if (kn < H_) {
            if (thAct) pTh = *(const uint4*)(thBase + kn);
            pZh = *(const uint4*)&Zb[(long)rz * H_ + kn + ckz];
            pZl = *(const uint4*)&Zb[zLo + (long)rz * H_ + kn + ckz];
        }
        short8 ah, al, zb[2], zl[2];
        ah = *(const short8*)&As2h[(wm2 + lr) * 40 + lq * 8];
        al = *(const short8*)&As2l[(wm2 + lr) * 40 + lq * 8];
#pragma unroll
        for (int nt = 0; nt < 2; ++nt) {
            zb[nt] = *(const short8*)&Zch[(wn2 + nt * 16 + lr) * 40 + lq * 8];
            zl[nt] = *(const short8*)&Zcl[(wn2 + nt * 16 + lr) * 40 + lq * 8];
        }
#pragma unroll
        for (int nt = 0; nt < 2; ++nt) {
            acc2[nt] = __builtin_amdgcn_mfma_f32_16x16x32_bf16(ah, zb[nt], acc2[nt], 0, 0, 0);
            acc2[nt] = __builtin_amdgcn_mfma_f32_16x16x32_bf16(ah, zl[nt], acc2[nt], 0, 0, 0);
            acc2[nt] = __builtin_amdgcn_mfma_f32_16x16x32_bf16(al, zb[nt], acc2[nt], 0, 0, 0);
        }
    }
    __syncthreads();
#pragma unroll
    for (int r4 = 0; r4 < 4; ++r4) {
        int row = wm2 + lq * 4 + r4;
#pragma unroll
        for (int nt = 0; nt < 2; ++nt) {
            int col = wn2 + nt * 16 + lr;
            float v = acc2[nt][r4];
            unsigned short hv = f2bf(v);
            Wh[row * WTPAD + col] = hv;
            Wl[row * WTPAD + col] = f2bf(v - bf2f(hv));
        }
    }
    __syncthreads();

    // ---- stage 3: hc^T[h 32][n 512] = Dinv[n]*sum_m W[h][m]*Hm[n][m] + cb --
    int wn3 = wave * 64;
    floatx4 acc3[2][4] = {};
    for (int k0 = 0; k0 < M_; k0 += 32) {
        short8 ah[2], al[2], bh3[4];
#pragma unroll
        for (int nt = 0; nt < 4; ++nt)
            bh3[nt] = *(const short8*)&Hm[(long)(wn3 + nt * 16 + lr) * M_ + k0 + lq * 8];
#pragma unroll
        for (int mt = 0; mt < 2; ++mt) {
            ah[mt] = *(const short8*)&Wh[(mt * 16 + lr) * WTPAD + k0 + lq * 8];
            al[mt] = *(const short8*)&Wl[(mt * 16 + lr) * WTPAD + k0 + lq * 8];
        }
#pragma unroll
        for (int mt = 0; mt < 2; ++mt)
#pragma unroll
            for (int nt = 0; nt < 4; ++nt) {
                acc3[mt][nt] = __builtin_amdgcn_mfma_f32_16x16x32_bf16(
                    ah[mt], bh3[nt], acc3[mt][nt], 0, 0, 0);
                acc3[mt][nt] = __builtin_amdgcn_mfma_f32_16x16x32_bf16(
                    al[mt], bh3[nt], acc3[mt][nt], 0, 0, 0);
            }
    }

    float dv[4];
#pragma unroll
    for (int nt = 0; nt < 4; ++nt)
        dv[nt] = DinvN[b * N_ + wn3 + nt * 16 + lr];
    float cb[2][4];
#pragma unroll
    for (int mt = 0; mt < 2; ++mt)
#pragma unroll
        for (int r4 = 0; r4 < 4; ++r4)
            cb[mt][r4] = convb[h0 + mt * 16 + lq * 4 + r4];
#pragma unroll
    for (int mt = 0; mt < 2; ++mt)
#pragma unroll
        for (int nt = 0; nt < 4; ++nt)
#pragma unroll
            for (int r4 = 0; r4 < 4; ++r4)
                acc3[mt][nt][r4] = acc3[mt][nt][r4] * dv[nt] + cb[mt][r4];

    float ps[2][4], pq[2][4];
#pragma unroll
    for (int mt = 0; mt < 2; ++mt)
#pragma unroll
        for (int r4 = 0; r4 < 4; ++r4) {
            float s = 0.f, q = 0.f;
#pragma unroll
            for (int nt = 0; nt < 4; ++nt) {
                float v = acc3[mt][nt][r4];
                s += v; q += v * v;
            }
            ps[mt][r4] = s; pq[mt][r4] = q;
        }
#pragma unroll
    for (int mask = 1; mask <= 8; mask <<= 1) {
#pragma unroll
        for (int mt = 0; mt < 2; ++mt)
#pragma unroll
            for (int r4 = 0; r4 < 4; ++r4) {
                ps[mt][r4] += __shfl_xor(ps[mt][r4], mask);
                pq[mt][r4] += __shfl_xor(pq[mt][r4], mask);
            }
    }
    if (lr == 0) {
#pragma unroll
        for (int mt = 0; mt < 2; ++mt)
#pragma unroll
            for (int r4 = 0; r4 < 4; ++r4) {
                int row = mt * 16 + lq * 4 + r4;
                rsum[row * 8 + wave] = ps[mt][r4];
                rsq[row * 8 + wave]  = pq[mt][r4];
            }
    }
    __syncthreads();
    if (tid < 32) {
        float s = 0.f, s2 = 0.f;
#pragma unroll
        for (int w = 0; w < 8; ++w) { s += rsum[tid * 8 + w]; s2 += rsq[tid * 8 + w]; }
        float mu  = s * (1.0f / N_);
        float var = fmaxf(s2 * (1.0f / N_) - mu * mu, 0.f);
        float sc  = gamma[h0 + tid] * rsqrtf(var + EPS_);
        prm[tid] = make_float2(sc, beta[h0 + tid] - mu * sc);
    }
    __syncthreads();

    unsigned short* ab = actOut + (long)b * H_ * N_;
#pragma unroll
    for (int mt = 0; mt < 2; ++mt)
#pragma unroll
        for (int r4 = 0; r4 < 4; ++r4) {
            int row = mt * 16 + lq * 4 + r4;
            float2 p = prm[row];
#pragma unroll
            for (int nt = 0; nt < 4; ++nt) {
                float y = fmaxf(acc3[mt][nt][r4] * p.x + p.y, 0.f);
                unsigned short hv = f2bf(y);
                long o = (long)(h0 + row) * N_ + wn3 + nt * 16 + lr;
                ab[o] = hv;
                ab[actLo + o] = f2bf(y - bf2f(hv));
            }
        }
}

// ===== decoder: out[n][p] = sum_h (hT[h][n]+act[h][n]) * Wdec[h][p] + bdec ==
// grid (8, B): block = (64 n-rows, batch). comb built on the fly in LDS.
__global__ __launch_bounds__(256, 2) void decoder_kernel(
    const unsigned short* __restrict__ actT, long actLo,
    const float* __restrict__ hT,
    const float* __restrict__ Wdec, const float* __restrict__ bdec,
    float* __restrict__ out)
{
    __shared__ float ct[64 * 65];      // [n][h-chunk] comb tile
    __shared__ float wd[256 * 25];     // whole Wdec, padded
    int n0 = blockIdx.x * 64, b = blockIdx.y;
    int tid = threadIdx.x;
    // stage Wdec once
    for (int i = tid; i < 256 * 24; i += 256)
        wd[(i / 24) * 25 + (i % 24)] = Wdec[i];

    const unsigned short* ab = actT + (long)b * H_ * N_;
    const float* hb = hT + (long)b * H_ * N_;
    int x = tid & 63, y0 = tid >> 6;

    int n = tid >> 2;
    int p0 = (tid & 3) * 6;
    float acc[6] = {};

    for (int k0 = 0; k0 < H_; k0 += 64) {
        __syncthreads();
#pragma unroll
        for (int i = 0; i < 16; ++i) {
            int y = y0 * 16 + i;                      // h-local
            long o = (long)(k0 + y) * N_ + n0 + x;
            ct[x * 65 + y] = hb[o] + bf2f(ab[o]) + bf2f(ab[actLo + o]);
        }
        __syncthreads();
        const float* crow = &ct[n * 65];
#pragma unroll 8
        for (int kk = 0; kk < 64; ++kk) {
            float a = crow[kk];
            const float* wrow = &wd[(k0 + kk) * 25 + p0];
#pragma unroll
            for (int j = 0; j < 6; ++j)
                acc[j] += a * wrow[j];
        }
    }
    long ob = ((long)b * N_ + n0 + n) * P2_ + p0;
#pragma unroll
    for (int j = 0; j < 6; ++j)
        out[ob + j] = acc[j] + bdec[p0 + j];
}

// --------------------------------------------------------------------------
extern "C" void kernel_launch(void* const* d_in, const int* in_sizes, int n_in,
                              void* d_out, int out_size, void* d_ws, size_t ws_size,
                              hipStream_t stream) {
    const float* obs    = (const float*)d_in[0];
    const int*   hyper  = (const int*)d_in[1];
    const float* Wenc   = (const float*)d_in[2];
    const float* benc   = (const float*)d_in[3];
    const float* thetas = (const float*)d_in[4];
    const float* convb  = (const float*)d_in[5];
    const float* gammas = (const float*)d_in[6];
    const float* betas  = (const float*)d_in[7];
    const float* Wdec   = (const float*)d_in[8];
    const float* bdec   = (const float*)d_in[9];
    float* out = (float*)d_out;

    char* w = (char*)d_ws;
    auto alloc = [&](size_t bytes) { char* p = w; w += (bytes + 255) & ~255ULL; return p; };
    float* hT    = (float*)alloc((size_t)B_ * H_ * N_ * 4);
    float* DinvN = (float*)alloc((size_t)B_ * N_ * 4);
    float* degM  = (float*)alloc((size_t)B_ * M_ * 4);
    unsigned short* Hmat  = (unsigned short*)alloc((size_t)B_ * N_ * M_ * 2);
    unsigned short* HmatT = (unsigned short*)alloc((size_t)B_ * M_ * N_ * 2);
    unsigned short* actA  = (unsigned short*)alloc((size_t)B_ * H_ * N_ * 2 * 2);
    unsigned short* actB  = (unsigned short*)alloc((size_t)B_ * H_ * N_ * 2 * 2);
    unsigned short* thT   = (unsigned short*)alloc((size_t)L_ * H_ * H_ * 2 * 2);
    unsigned short* Zg    = (unsigned short*)alloc((size_t)B_ * M_ * H_ * 2 * 2);

    const long actLo = (long)B_ * H_ * N_;
    const long thLo  = (long)L_ * H_ * H_;
    const long zLo   = (long)B_ * M_ * H_;

    hipMemsetAsync(degM, 0, (size_t)B_ * M_ * 4, stream);
    prep_kernel<<<816, 512, 0, stream>>>(
        obs, Wenc, benc, hT, actA, actLo,
        hyper, Hmat, HmatT, DinvN, degM,
        thetas, thT, thLo);

    const unsigned short* cur = actA;
    unsigned short* nxt = actB;
    for (int l = 0; l < L_; ++l) {
        z_kernel<<<dim3(B_, 4), 256, 0, stream>>>(
            HmatT, cur, actLo, degM, Zg, zLo);
        wh_kernel<<<512, 512, 0, stream>>>(
            Zg, zLo, Hmat, thT + (size_t)l * H_ * H_, thLo,
            DinvN, convb + (size_t)l * H_,
            gammas + (size_t)l * H_, betas + (size_t)l * H_, nxt, actLo);
        const unsigned short* t = cur; cur = nxt; nxt = (unsigned short*)t;
    }
    // fused comb + decoder
    decoder_kernel<<<dim3(8, B_), 256, 0, stream>>>(
        cur, actLo, hT, Wdec, bdec, out);
}

// Round 11
// 226.506 us; speedup vs baseline: 2.0059x; 1.0108x over previous
//
#include <hip/hip_runtime.h>
#include <hip/hip_bf16.h>

#define B_   64
#define N_   512
#define T_   8
#define DIN_ 2
#define H_   256
#define L_   3
#define E_   8192
#define M_   128
#define P2_  24   // P*2
#define EPS_ 1e-5f

#define WTPAD 136

typedef __attribute__((ext_vector_type(8))) short short8;
typedef __attribute__((ext_vector_type(4))) float floatx4;

__device__ __forceinline__ unsigned short f2bf(float f) {
    union { float f; unsigned u; } v; v.f = f;
    unsigned r = v.u + 0x7FFF + ((v.u >> 16) & 1);
    return (unsigned short)(r >> 16);
}
__device__ __forceinline__ float bf2f(unsigned short h) {
    union { unsigned u; float f; } v; v.u = (unsigned)h << 16; return v.f;
}

// ===== prep: encoder (256 blks) + incidence build (512 blks) + thetaT (48) ==
// encoder writes ONLY split actT (h lives in the hi/lo planes; no fp32 copy)
__global__ __launch_bounds__(512, 4) void prep_kernel(
    const float* __restrict__ obs, const float* __restrict__ Wenc,
    const float* __restrict__ benc,
    unsigned short* __restrict__ actT, long actLo,
    const int* __restrict__ idx, unsigned short* __restrict__ Hmat,
    unsigned short* __restrict__ HmatT, float* __restrict__ DinvN,
    float* __restrict__ degM,
    const float* __restrict__ thetas, unsigned short* __restrict__ thT, long thLo)
{
    __shared__ __align__(16) char u[33024];
    int bid = blockIdx.x, tid = threadIdx.x;
    if (bid < 256) {
        float* ot = (float*)u;   // [16][513]
        int b = bid >> 2, h0 = (bid & 3) * 64;
        const float4* src = (const float4*)(obs + (long)b * N_ * 16);
        for (int i = tid; i < 2048; i += 512) {
            float4 v = src[i];
            int n = i >> 2, k4 = (i & 3) << 2;
            ot[(k4 + 0) * 513 + n] = v.x;
            ot[(k4 + 1) * 513 + n] = v.y;
            ot[(k4 + 2) * 513 + n] = v.z;
            ot[(k4 + 3) * 513 + n] = v.w;
        }
        __syncthreads();
        int wave = tid >> 6, lane = tid & 63;
        int cbase = h0 + wave * 8;
        float w0[8], w1[8], bb[8];
#pragma unroll
        for (int i = 0; i < 8; ++i) {
            w0[i] = Wenc[cbase + i];
            w1[i] = Wenc[H_ + cbase + i];
            bb[i] = benc[cbase + i];
        }
        for (int j = 0; j < 8; ++j) {
            int n = j * 64 + lane;
            float x0[8], x1[8];
#pragma unroll
            for (int t = 0; t < 8; ++t) {
                x0[t] = ot[(2 * t) * 513 + n];
                x1[t] = ot[(2 * t + 1) * 513 + n];
            }
#pragma unroll
            for (int i = 0; i < 8; ++i) {
                float acc = 0.f;
#pragma unroll
                for (int t = 0; t < 8; ++t)
                    acc += fmaxf(x0[t] * w0[i] + x1[t] * w1[i] + bb[i], 0.f);
                acc *= 0.125f;
                long o = ((long)b * H_ + cbase + i) * N_ + n;
                unsigned short hv = f2bf(acc);
                actT[o] = hv;
                actT[actLo + o] = f2bf(acc - bf2f(hv));
            }
        }
    } else if (bid < 768) {
        unsigned* cnt = (unsigned*)u;    // [64][129]
        int id2 = bid - 256;
        int b = id2 >> 3, chunk = id2 & 7;
        int c0 = chunk * 64;
        for (int i = tid; i < 64 * 129; i += 512) cnt[i] = 0;
        __syncthreads();
        const int* nodes = idx + (long)b * 2 * E_;
        const int* edges = nodes + E_;
        for (int e = tid; e < E_; e += 512) {
            int n = nodes[e];
            if ((n >> 6) == chunk) atomicAdd(&cnt[(n & 63) * 129 + edges[e]], 1u);
        }
        __syncthreads();
        for (int i = tid; i < 64 * 128; i += 512) {
            int r = i >> 7, m = i & 127;
            Hmat[((long)(b * N_ + c0 + r)) * M_ + m] = f2bf((float)cnt[r * 129 + m]);
        }
        for (int i = tid; i < 64 * 128; i += 512) {
            int m = i >> 6, r = i & 63;
            HmatT[((long)(b * M_ + m)) * N_ + c0 + r] = f2bf((float)cnt[r * 129 + m]);
        }
        if (tid < 64) {
            unsigned s = 0;
#pragma unroll 8
            for (int m = 0; m < 128; ++m) s += cnt[tid * 129 + m];
            DinvN[b * N_ + c0 + tid] = 1.0f / fmaxf((float)s, 1.0f);
        } else if (tid < 192) {
            int m = tid - 64;
            unsigned s = 0;
#pragma unroll 8
            for (int r = 0; r < 64; ++r) s += cnt[r * 129 + m];
            atomicAdd(&degM[b * M_ + m], (float)s);
        }
    } else {
        float (*tile)[65] = (float(*)[65])u;
        int sub = bid - 768;                 // 0..47
        int cx = sub & 3, ry = (sub >> 2) & 3, l = sub >> 4;
        int r0 = ry * 64, c0 = cx * 64;
        const float* ib = thetas + (long)l * H_ * H_;
        unsigned short* ob = thT + (long)l * H_ * H_;
        int x = tid & 63, y0 = tid >> 6;
#pragma unroll
        for (int i = 0; i < 8; ++i) {
            int y = y0 * 8 + i;
            tile[y][x] = ib[(long)(r0 + y) * H_ + c0 + x];
        }
        __syncthreads();
#pragma unroll
        for (int i = 0; i < 8; ++i) {
            int y = y0 * 8 + i;
            float v = tile[x][y];
            unsigned short hv = f2bf(v);
            long o = (long)(c0 + y) * H_ + r0 + x;
            ob[o] = hv;
            ob[thLo + o] = f2bf(v - bf2f(hv));
        }
    }
}

// ===== z: Z[m][h'] = (1/max(degM,1)) * sum_n HT[m][n]*act[h'][n], split out ==
// grid (64, 4): block (b, q) computes cols q*64..+63. id%8 = b%8 (XCD-local).
__global__ __launch_bounds__(256, 4) void z_kernel(
    const unsigned short* __restrict__ HmatT,
    const unsigned short* __restrict__ actIn, long actLo,
    const float* __restrict__ degM,
    unsigned short* __restrict__ Zg, long zLo)
{
    __shared__ __align__(16) unsigned short As1[128 * 40];
    __shared__ __align__(16) unsigned short Bh[64 * 40];
    __shared__ __align__(16) unsigned short Bl[64 * 40];
    int b = blockIdx.x, hs = blockIdx.y * 64;
    int tid = threadIdx.x, wave = tid >> 6, lane = tid & 63;
    int lr = lane & 15, lq = lane >> 4;
    int wm = (wave & 1) * 64, wn = (wave >> 1) * 32;
    const unsigned short* HT   = HmatT + (long)b * M_ * N_;
    const unsigned short* aInH = actIn + (long)b * H_ * N_ + (long)hs * N_;
    const unsigned short* aInL = actIn + actLo + (long)b * H_ * N_ + (long)hs * N_;

    floatx4 acc[4][2] = {};
    int r0 = tid >> 2, ck = (tid & 3) << 3;
    int r1 = r0 + 64;
    uint4 pA0 = *(const uint4*)&HT[(long)r0 * N_ + ck];
    uint4 pA1 = *(const uint4*)&HT[(long)r1 * N_ + ck];
    uint4 pBh = *(const uint4*)&aInH[(long)r0 * N_ + ck];
    uint4 pBl = *(const uint4*)&aInL[(long)r0 * N_ + ck];
    for (int k0 = 0; k0 < N_; k0 += 32) {
        __syncthreads();
        *(uint4*)&As1[r0 * 40 + ck] = pA0;
        *(uint4*)&As1[r1 * 40 + ck] = pA1;
        *(uint4*)&Bh[r0 * 40 + ck]  = pBh;
        *(uint4*)&Bl[r0 * 40 + ck]  = pBl;
        __syncthreads();
        int kn = k0 + 32;
        if (kn < N_) {
            pA0 = *(const uint4*)&HT[(long)r0 * N_ + kn + ck];
            pA1 = *(const uint4*)&HT[(long)r1 * N_ + kn + ck];
            pBh = *(const uint4*)&aInH[(long)r0 * N_ + kn + ck];
            pBl = *(const uint4*)&aInL[(long)r0 * N_ + kn + ck];
        }
        short8 af[4], bh[2], bl[2];
#pragma unroll
        for (int mt = 0; mt < 4; ++mt)
            af[mt] = *(const short8*)&As1[(wm + mt * 16 + lr) * 40 + lq * 8];
#pragma unroll
        for (int nt = 0; nt < 2; ++nt) {
            bh[nt] = *(const short8*)&Bh[(wn + nt * 16 + lr) * 40 + lq * 8];
            bl[nt] = *(const short8*)&Bl[(wn + nt * 16 + lr) * 40 + lq * 8];
        }
#pragma unroll
        for (int mt = 0; mt < 4; ++mt)
#pragma unroll
            for (int nt = 0; nt < 2; ++nt) {
                acc[mt][nt] = __builtin_amdgcn_mfma_f32_16x16x32_bf16(
                    af[mt], bh[nt], acc[mt][nt], 0, 0, 0);
                acc[mt][nt] = __builtin_amdgcn_mfma_f32_16x16x32_bf16(
                    af[mt], bl[nt], acc[mt][nt], 0, 0, 0);
            }
    }
#pragma unroll
    for (int mt = 0; mt < 4; ++mt)
#pragma unroll
        for (int r4 = 0; r4 < 4; ++r4) {
            int m = wm + mt * 16 + lq * 4 + r4;
            float rsB = 1.0f / fmaxf(degM[b * M_ + m], 1.0f);
#pragma unroll
            for (int nt = 0; nt < 2; ++nt) {
                float v = acc[mt][nt][r4] * rsB;
                unsigned short hv = f2bf(v);
                long o = ((long)b * M_ + m) * H_ + hs + wn + nt * 16 + lr;
                Zg[o] = hv;
                Zg[zLo + o] = f2bf(v - bf2f(hv));
            }
        }
}

// ===== wh: W=Theta^T Z^T ; hc^T=Dinv(W Hm^T)+cb ; BN ; ReLU ; split write ==
__global__ __launch_bounds__(512, 4) void wh_kernel(
    const unsigned short* __restrict__ Zg, long zLo,
    const unsigned short* __restrict__ Hmat,
    const unsigned short* __restrict__ thT, long thLo,   // pre-offset to layer
    const float* __restrict__ DinvN, const float* __restrict__ convb,
    const float* __restrict__ gamma, const float* __restrict__ beta,
    unsigned short* __restrict__ actOut, long actLo)
{
    __shared__ __align__(16) char lds[28160];
    unsigned short* Zch  = (unsigned short*)lds;            // [128][40]
    unsigned short* Zcl  = Zch + 128 * 40;
    unsigned short* As2h = Zcl + 128 * 40;                  // [32][40]
    unsigned short* As2l = As2h + 32 * 40;                  // end 25600 B
    unsigned short* Wh   = (unsigned short*)lds;            // [32][136] overlap
    unsigned short* Wl   = Wh + 32 * WTPAD;                 // end 17408 B
    float* rsum = (float*)(lds + 25600);                    // [32][8]
    float* rsq  = rsum + 256;
    float2* prm = (float2*)(rsq + 256);                     // [32]

    int id = blockIdx.x;
    int xcd = id & 7, slot = id >> 3;
    int chunk = slot & 7;
    int b  = ((slot >> 3) << 3) | xcd;
    int h0 = chunk * 32;

    int tid = threadIdx.x, wave = tid >> 6, lane = tid & 63;
    int lr = lane & 15, lq = lane >> 4;
    const unsigned short* Zb = Zg + (long)b * M_ * H_;
    const unsigned short* Hm = Hmat + (long)b * N_ * M_;

    // ---- stage 2: W[h 32][m 128] = sum_h' thT[h][h'] * Z[m][h'] ----
    int wm2 = (wave >> 2) * 16, wn2 = (wave & 3) * 32;
    int i2 = tid & 255, pl2 = tid >> 8;
    int r2 = i2 >> 2, ck2 = (i2 & 3) << 3;
    bool thAct = (i2 < 128);
    const unsigned short* thBase = thT + (pl2 ? thLo : 0) + (long)(h0 + r2) * H_ + ck2;
    unsigned short* As2dst = (pl2 ? As2l : As2h) + r2 * 40 + ck2;
    int rz = tid >> 2, ckz = (tid & 3) << 3;
    uint4 pTh = {};
    if (thAct) pTh = *(const uint4*)thBase;
    uint4 pZh = *(const uint4*)&Zb[(long)rz * H_ + ckz];
    uint4 pZl = *(const uint4*)&Zb[zLo + (long)rz * H_ + ckz];
    floatx4 acc2[2] = {};
    for (int k0 = 0; k0 < H_; k0 += 32) {
        __syncthreads();
        if (thAct) *(uint4*)As2dst = pTh;
        *(uint4*)&Zch[rz * 40 + ckz] = pZh;
        *(uint4*)&Zcl[rz * 40 + ckz] = pZl;
        __syncthreads();
        int kn = k0 + 32;
        if (kn < H_) {
            if (thAct) pTh = *(const uint4*)(thBase + kn);
            pZh = *(const uint4*)&Zb[(long)rz * H_ + kn + ckz];
            pZl = *(const uint4*)&Zb[zLo + (long)rz * H_ + kn + ckz];
        }
        short8 ah, al, zb[2], zl[2];
        ah = *(const short8*)&As2h[(wm2 + lr) * 40 + lq * 8];
        al = *(const short8*)&As2l[(wm2 + lr) * 40 + lq * 8];
#pragma unroll
        for (int nt = 0; nt < 2; ++nt) {
            zb[nt] = *(const short8*)&Zch[(wn2 + nt * 16 + lr) * 40 + lq * 8];
            zl[nt] = *(const short8*)&Zcl[(wn2 + nt * 16 + lr) * 40 + lq * 8];
        }
#pragma unroll
        for (int nt = 0; nt < 2; ++nt) {
            acc2[nt] = __builtin_amdgcn_mfma_f32_16x16x32_bf16(ah, zb[nt], acc2[nt], 0, 0, 0);
            acc2[nt] = __builtin_amdgcn_mfma_f32_16x16x32_bf16(ah, zl[nt], acc2[nt], 0, 0, 0);
            acc2[nt] = __builtin_amdgcn_mfma_f32_16x16x32_bf16(al, zb[nt], acc2[nt], 0, 0, 0);
        }
    }
    __syncthreads();
#pragma unroll
    for (int r4 = 0; r4 < 4; ++r4) {
        int row = wm2 + lq * 4 + r4;
#pragma unroll
        for (int nt = 0; nt < 2; ++nt) {
            int col = wn2 + nt * 16 + lr;
            float v = acc2[nt][r4];
            unsigned short hv = f2bf(v);
            Wh[row * WTPAD + col] = hv;
            Wl[row * WTPAD + col] = f2bf(v - bf2f(hv));
        }
    }
    __syncthreads();

    // ---- stage 3: hc^T[h 32][n 512] = Dinv[n]*sum_m W[h][m]*Hm[n][m] + cb --
    int wn3 = wave * 64;
    floatx4 acc3[2][4] = {};
    for (int k0 = 0; k0 < M_; k0 += 32) {
        short8 ah[2], al[2], bh3[4];
#pragma unroll
        for (int nt = 0; nt < 4; ++nt)
            bh3[nt] = *(const short8*)&Hm[(long)(wn3 + nt * 16 + lr) * M_ + k0 + lq * 8];
#pragma unroll
        for (int mt = 0; mt < 2; ++mt) {
            ah[mt] = *(const short8*)&Wh[(mt * 16 + lr) * WTPAD + k0 + lq * 8];
            al[mt] = *(const short8*)&Wl[(mt * 16 + lr) * WTPAD + k0 + lq * 8];
        }
#pragma unroll
        for (int mt = 0; mt < 2; ++mt)
#pragma unroll
            for (int nt = 0; nt < 4; ++nt) {
                acc3[mt][nt] = __builtin_amdgcn_mfma_f32_16x16x32_bf16(
                    ah[mt], bh3[nt], acc3[mt][nt], 0, 0, 0);
                acc3[mt][nt] = __builtin_amdgcn_mfma_f32_16x16x32_bf16(
                    al[mt], bh3[nt], acc3[mt][nt], 0, 0, 0);
            }
    }

    float dv[4];
#pragma unroll
    for (int nt = 0; nt < 4; ++nt)
        dv[nt] = DinvN[b * N_ + wn3 + nt * 16 + lr];
    float cb[2][4];
#pragma unroll
    for (int mt = 0; mt < 2; ++mt)
#pragma unroll
        for (int r4 = 0; r4 < 4; ++r4)
            cb[mt][r4] = convb[h0 + mt * 16 + lq * 4 + r4];
#pragma unroll
    for (int mt = 0; mt < 2; ++mt)
#pragma unroll
        for (int nt = 0; nt < 4; ++nt)
#pragma unroll
            for (int r4 = 0; r4 < 4; ++r4)
                acc3[mt][nt][r4] = acc3[mt][nt][r4] * dv[nt] + cb[mt][r4];

    float ps[2][4], pq[2][4];
#pragma unroll
    for (int mt = 0; mt < 2; ++mt)
#pragma unroll
        for (int r4 = 0; r4 < 4; ++r4) {
            float s = 0.f, q = 0.f;
#pragma unroll
            for (int nt = 0; nt < 4; ++nt) {
                float v = acc3[mt][nt][r4];
                s += v; q += v * v;
            }
            ps[mt][r4] = s; pq[mt][r4] = q;
        }
#pragma unroll
    for (int mask = 1; mask <= 8; mask <<= 1) {
#pragma unroll
        for (int mt = 0; mt < 2; ++mt)
#pragma unroll
            for (int r4 = 0; r4 < 4; ++r4) {
                ps[mt][r4] += __shfl_xor(ps[mt][r4], mask);
                pq[mt][r4] += __shfl_xor(pq[mt][r4], mask);
            }
    }
    if (lr == 0) {
#pragma unroll
        for (int mt = 0; mt < 2; ++mt)
#pragma unroll
            for (int r4 = 0; r4 < 4; ++r4) {
                int row = mt * 16 + lq * 4 + r4;
                rsum[row * 8 + wave] = ps[mt][r4];
                rsq[row * 8 + wave]  = pq[mt][r4];
            }
    }
    __syncthreads();
    if (tid < 32) {
        float s = 0.f, s2 = 0.f;
#pragma unroll
        for (int w = 0; w < 8; ++w) { s += rsum[tid * 8 + w]; s2 += rsq[tid * 8 + w]; }
        float mu  = s * (1.0f / N_);
        float var = fmaxf(s2 * (1.0f / N_) - mu * mu, 0.f);
        float sc  = gamma[h0 + tid] * rsqrtf(var + EPS_);
        prm[tid] = make_float2(sc, beta[h0 + tid] - mu * sc);
    }
    __syncthreads();

    unsigned short* ab = actOut + (long)b * H_ * N_;
#pragma unroll
    for (int mt = 0; mt < 2; ++mt)
#pragma unroll
        for (int r4 = 0; r4 < 4; ++r4) {
            int row = mt * 16 + lq * 4 + r4;
            float2 p = prm[row];
#pragma unroll
            for (int nt = 0; nt < 4; ++nt) {
                float y = fmaxf(acc3[mt][nt][r4] * p.x + p.y, 0.f);
                unsigned short hv = f2bf(y);
                long o = (long)(h0 + row) * N_ + wn3 + nt * 16 + lr;
                ab[o] = hv;
                ab[actLo + o] = f2bf(y - bf2f(hv));
            }
        }
}

// ===== decoder: out[n][p] = sum_h (h[h][n]+act[h][n]) * Wdec[h][p] + bdec ==
// reads only the HI planes of h and h_social (error ~1e-3 << threshold)
__global__ __launch_bounds__(256, 2) void decoder_kernel(
    const unsigned short* __restrict__ hAct,   // h hi plane [B][H][N]
    const unsigned short* __restrict__ sAct,   // social hi plane
    const float* __restrict__ Wdec, const float* __restrict__ bdec,
    float* __restrict__ out)
{
    __shared__ float ct[64 * 65];      // [n][h-chunk] comb tile
    __shared__ float wd[256 * 25];     // whole Wdec, padded
    int n0 = blockIdx.x * 64, b = blockIdx.y;
    int tid = threadIdx.x;
    for (int i = tid; i < 256 * 24; i += 256)
        wd[(i / 24) * 25 + (i % 24)] = Wdec[i];

    const unsigned short* hb = hAct + (long)b * H_ * N_;
    const unsigned short* sb = sAct + (long)b * H_ * N_;
    int x = tid & 63, y0 = tid >> 6;

    int n = tid >> 2;
    int p0 = (tid & 3) * 6;
    float acc[6] = {};

    for (int k0 = 0; k0 < H_; k0 += 64) {
        __syncthreads();
#pragma unroll
        for (int i = 0; i < 16; ++i) {
            int y = y0 * 16 + i;                      // h-local
            long o = (long)(k0 + y) * N_ + n0 + x;
            ct[x * 65 + y] = bf2f(hb[o]) + bf2f(sb[o]);
        }
        __syncthreads();
        const float* crow = &ct[n * 65];
#pragma unroll 8
        for (int kk = 0; kk < 64; ++kk) {
            float a = crow[kk];
            const float* wrow = &wd[(k0 + kk) * 25 + p0];
#pragma unroll
            for (int j = 0; j < 6; ++j)
                acc[j] += a * wrow[j];
        }
    }
    long ob = ((long)b * N_ + n0 + n) * P2_ + p0;
#pragma unroll
    for (int j = 0; j < 6; ++j)
        out[ob + j] = acc[j] + bdec[p0 + j];
}

// --------------------------------------------------------------------------
extern "C" void kernel_launch(void* const* d_in, const int* in_sizes, int n_in,
                              void* d_out, int out_size, void* d_ws, size_t ws_size,
                              hipStream_t stream) {
    const float* obs    = (const float*)d_in[0];
    const int*   hyper  = (const int*)d_in[1];
    const float* Wenc   = (const float*)d_in[2];
    const float* benc   = (const float*)d_in[3];
    const float* thetas = (const float*)d_in[4];
    const float* convb  = (const float*)d_in[5];
    const float* gammas = (const float*)d_in[6];
    const float* betas  = (const float*)d_in[7];
    const float* Wdec   = (const float*)d_in[8];
    const float* bdec   = (const float*)d_in[9];
    float* out = (float*)d_out;

    char* w = (char*)d_ws;
    auto alloc = [&](size_t bytes) { char* p = w; w += (bytes + 255) & ~255ULL; return p; };
    float* DinvN = (float*)alloc((size_t)B_ * N_ * 4);
    float* degM  = (float*)alloc((size_t)B_ * M_ * 4);
    unsigned short* Hmat  = (unsigned short*)alloc((size_t)B_ * N_ * M_ * 2);
    unsigned short* HmatT = (unsigned short*)alloc((size_t)B_ * M_ * N_ * 2);
    unsigned short* act0  = (unsigned short*)alloc((size_t)B_ * H_ * N_ * 2 * 2);
    unsigned short* act1  = (unsigned short*)alloc((size_t)B_ * H_ * N_ * 2 * 2);
    unsigned short* act2  = (unsigned short*)alloc((size_t)B_ * H_ * N_ * 2 * 2);
    unsigned short* thT   = (unsigned short*)alloc((size_t)L_ * H_ * H_ * 2 * 2);
    unsigned short* Zg    = (unsigned short*)alloc((size_t)B_ * M_ * H_ * 2 * 2);

    const long actLo = (long)B_ * H_ * N_;
    const long thLo  = (long)L_ * H_ * H_;
    const long zLo   = (long)B_ * M_ * H_;

    hipMemsetAsync(degM, 0, (size_t)B_ * M_ * 4, stream);
    prep_kernel<<<816, 512, 0, stream>>>(
        obs, Wenc, benc, act0, actLo,
        hyper, Hmat, HmatT, DinvN, degM,
        thetas, thT, thLo);

    // act0 stays pristine as h; layers rotate act0 -> act1 -> act2 -> act1
    unsigned short* bufs[4] = { act0, act1, act2, act1 };
    for (int l = 0; l < L_; ++l) {
        z_kernel<<<dim3(B_, 4), 256, 0, stream>>>(
            HmatT, bufs[l], actLo, degM, Zg, zLo);
        wh_kernel<<<512, 512, 0, stream>>>(
            Zg, zLo, Hmat, thT + (size_t)l * H_ * H_, thLo,
            DinvN, convb + (size_t)l * H_,
            gammas + (size_t)l * H_, betas + (size_t)l * H_, bufs[l + 1], actLo);
    }
    // fused comb + decoder: h = act0 hi, social = act1 hi (layer-2 output)
    decoder_kernel<<<dim3(8, B_), 256, 0, stream>>>(
        act0, bufs[L_], Wdec, bdec, out);
}